// Round 8
// baseline (287.305 us; speedup 1.0000x reference)
//
#include <hip/hip_runtime.h>

#define HH 256   // H
#define BB 64    // B
#define KK 32    // K
#define LL 64    // L
#define LGRP 8   // l's per edge-kernel block

typedef __bf16 bf16_t;
typedef __attribute__((ext_vector_type(8))) __bf16 bf16x8;
typedef __attribute__((ext_vector_type(4))) float f32x4;

// ---- load 8 contiguous f32 -> bf16x8 ----
__device__ __forceinline__ bf16x8 ld_a8(const float* __restrict__ p) {
  const f32x4* q = (const f32x4*)p;
  f32x4 a = q[0], b = q[1];
  bf16x8 r;
  r[0] = (__bf16)a[0]; r[1] = (__bf16)a[1]; r[2] = (__bf16)a[2]; r[3] = (__bf16)a[3];
  r[4] = (__bf16)b[0]; r[5] = (__bf16)b[1]; r[6] = (__bf16)b[2]; r[7] = (__bf16)b[3];
  return r;
}
__device__ __forceinline__ bf16x8 ld_a8s(const float* __restrict__ p, float sc) {
  const f32x4* q = (const f32x4*)p;
  f32x4 a = q[0], b = q[1];
  bf16x8 r;
  r[0] = (__bf16)(a[0]*sc); r[1] = (__bf16)(a[1]*sc); r[2] = (__bf16)(a[2]*sc); r[3] = (__bf16)(a[3]*sc);
  r[4] = (__bf16)(b[0]*sc); r[5] = (__bf16)(b[1]*sc); r[6] = (__bf16)(b[2]*sc); r[7] = (__bf16)(b[3]*sc);
  return r;
}
// sum 8 partial slices (stride 524288 f32) -> bf16x8
__device__ __forceinline__ bf16x8 ld_sum8(const float* __restrict__ p) {
  f32x4 s0 = {0.f,0.f,0.f,0.f}, s1 = s0;
#pragma unroll
  for (int lc = 0; lc < 8; ++lc) {
    const f32x4* q = (const f32x4*)(p + (size_t)lc * 524288);
    s0 += q[0]; s1 += q[1];
  }
  bf16x8 r;
  r[0] = (__bf16)s0[0]; r[1] = (__bf16)s0[1]; r[2] = (__bf16)s0[2]; r[3] = (__bf16)s0[3];
  r[4] = (__bf16)s1[0]; r[5] = (__bf16)s1[1]; r[6] = (__bf16)s1[2]; r[7] = (__bf16)s1[3];
  return r;
}

// ---- e-tile staging (512 threads): 16 f32/thread -> regs -> swizzled bf16 LDS ----
__device__ __forceinline__ void ld_tile(const float* __restrict__ E, int tid, f32x4 r[4]) {
  const f32x4* q = (const f32x4*)(E + tid * 16);
  r[0] = q[0]; r[1] = q[1]; r[2] = q[2]; r[3] = q[3];
}
__device__ __forceinline__ void wr_tile(bf16_t* buf, int tid, const f32x4 r[4]) {
  int row = tid >> 4;
  int colb = (tid & 15) * 32;
  bf16x8 v0, v1;
  v0[0] = (__bf16)r[0][0]; v0[1] = (__bf16)r[0][1]; v0[2] = (__bf16)r[0][2]; v0[3] = (__bf16)r[0][3];
  v0[4] = (__bf16)r[1][0]; v0[5] = (__bf16)r[1][1]; v0[6] = (__bf16)r[1][2]; v0[7] = (__bf16)r[1][3];
  v1[0] = (__bf16)r[2][0]; v1[1] = (__bf16)r[2][1]; v1[2] = (__bf16)r[2][2]; v1[3] = (__bf16)r[2][3];
  v1[4] = (__bf16)r[3][0]; v1[5] = (__bf16)r[3][1]; v1[6] = (__bf16)r[3][2]; v1[7] = (__bf16)r[3][3];
  int swz = (row & 7) << 4;
  *(bf16x8*)((char*)buf + row * 512 + (colb ^ swz)) = v0;
  *(bf16x8*)((char*)buf + row * 512 + ((colb + 16) ^ swz)) = v1;
}

// acc[2][4] += A(32x256 f32 global)*B(bf16 row-major)^T  (4-wave, 64-col wave)
template<int LDB>
__device__ __forceinline__ void mm_f32A(const float* __restrict__ A,
                                        const bf16_t* __restrict__ B,
                                        f32x4 acc[2][4], int lane) {
  const int c = lane & 15, g = lane >> 4;
#pragma unroll
  for (int ks = 0; ks < 8; ++ks) {
    const int ko = ks * 32 + g * 8;
    bf16x8 a0 = ld_a8(A + (size_t)c * HH + ko);
    bf16x8 a1 = ld_a8(A + (size_t)(16 + c) * HH + ko);
#pragma unroll
    for (int nt = 0; nt < 4; ++nt) {
      bf16x8 bb = *(const bf16x8*)(B + (size_t)(nt * 16 + c) * LDB + ko);
      acc[0][nt] = __builtin_amdgcn_mfma_f32_16x16x32_bf16(a0, bb, acc[0][nt], 0, 0, 0);
      acc[1][nt] = __builtin_amdgcn_mfma_f32_16x16x32_bf16(a1, bb, acc[1][nt], 0, 0, 0);
    }
  }
}

// acc[2][4] += A(32x256 f32 global)*B(f32 global, cvt+scale)^T
template<int LDB>
__device__ __forceinline__ void mm_f32AB(const float* __restrict__ A,
                                         const float* __restrict__ B,
                                         f32x4 acc[2][4], int lane, float sc) {
  const int c = lane & 15, g = lane >> 4;
#pragma unroll
  for (int ks = 0; ks < 8; ++ks) {
    const int ko = ks * 32 + g * 8;
    bf16x8 a0 = ld_a8(A + (size_t)c * HH + ko);
    bf16x8 a1 = ld_a8(A + (size_t)(16 + c) * HH + ko);
#pragma unroll
    for (int nt = 0; nt < 4; ++nt) {
      bf16x8 bb = ld_a8s(B + (size_t)(nt * 16 + c) * LDB + ko, sc);
      acc[0][nt] = __builtin_amdgcn_mfma_f32_16x16x32_bf16(a0, bb, acc[0][nt], 0, 0, 0);
      acc[1][nt] = __builtin_amdgcn_mfma_f32_16x16x32_bf16(a1, bb, acc[1][nt], 0, 0, 0);
    }
  }
}

// acc[2][4] += (Σ_lc part)(32x256)*B(f32, cvt+scale)^T — reduce fused into A-fragments
__device__ __forceinline__ void mm_partA(const float* __restrict__ P,
                                         const float* __restrict__ B,
                                         f32x4 acc[2][4], int lane, float sc) {
  const int c = lane & 15, g = lane >> 4;
#pragma unroll
  for (int ks = 0; ks < 8; ++ks) {
    const int ko = ks * 32 + g * 8;
    bf16x8 a0 = ld_sum8(P + (size_t)c * HH + ko);
    bf16x8 a1 = ld_sum8(P + (size_t)(16 + c) * HH + ko);
#pragma unroll
    for (int nt = 0; nt < 4; ++nt) {
      bf16x8 bb = ld_a8s(B + (size_t)(nt * 16 + c) * HH + ko, sc);
      acc[0][nt] = __builtin_amdgcn_mfma_f32_16x16x32_bf16(a0, bb, acc[0][nt], 0, 0, 0);
      acc[1][nt] = __builtin_amdgcn_mfma_f32_16x16x32_bf16(a1, bb, acc[1][nt], 0, 0, 0);
    }
  }
}

// acc[2][4] += A(32x256 bf16 global row-major)*B(f32 global cvt)^T
__device__ __forceinline__ void mm_bf16A_f32B(const bf16_t* __restrict__ A,
                                              const float* __restrict__ B,
                                              f32x4 acc[2][4], int lane) {
  const int c = lane & 15, g = lane >> 4;
#pragma unroll
  for (int ks = 0; ks < 8; ++ks) {
    const int ko = ks * 32 + g * 8;
    bf16x8 a0 = *(const bf16x8*)(A + (size_t)c * HH + ko);
    bf16x8 a1 = *(const bf16x8*)(A + (size_t)(16 + c) * HH + ko);
#pragma unroll
    for (int nt = 0; nt < 4; ++nt) {
      bf16x8 bb = ld_a8(B + (size_t)(nt * 16 + c) * HH + ko);
      acc[0][nt] = __builtin_amdgcn_mfma_f32_16x16x32_bf16(a0, bb, acc[0][nt], 0, 0, 0);
      acc[1][nt] = __builtin_amdgcn_mfma_f32_16x16x32_bf16(a1, bb, acc[1][nt], 0, 0, 0);
    }
  }
}

// ---------------- prep: the 4 matrices consumed as bf16 by the edge kernels ----------------
__global__ __launch_bounds__(256) void prep_kernel(
    const float* w0, const float* w1, const float* w2, const float* w3, bf16_t* wb) {
  int i = blockIdx.x * 256 + threadIdx.x;
  const float* s; int o;
  if      (i < 131072) { s = w0; o = i; }
  else if (i < 262144) { s = w1; o = i - 131072; }
  else if (i < 458752) { s = w2; o = i - 262144; }
  else                 { s = w3; o = i - 458752; }
  wb[i] = (__bf16)s[o];
}

// ---------------- fused pair of projections: out = X*W^T + bias (bf16 W) ----------------
template<int LDW>
__global__ __launch_bounds__(256) void proj2_kernel(
    const float* __restrict__ X0, const bf16_t* __restrict__ W0,
    const float* __restrict__ b0, float* __restrict__ out0, int n0,
    const float* __restrict__ X1, const bf16_t* __restrict__ W1,
    const float* __restrict__ b1, float* __restrict__ out1) {
  const int blk = blockIdx.x;
  const float* X; const bf16_t* W; const float* bias; float* out; int row0;
  if (blk < n0) { X = X0; W = W0; bias = b0; out = out0; row0 = blk * 32; }
  else          { X = X1; W = W1; bias = b1; out = out1; row0 = (blk - n0) * 32; }
  const int tid = threadIdx.x, w = tid >> 6, lane = tid & 63;
  const int colw = w * 64, c = lane & 15, g = lane >> 4;
  f32x4 acc[2][4];
#pragma unroll
  for (int nt = 0; nt < 4; ++nt) {
    float bv = bias ? bias[colw + nt * 16 + c] : 0.f;
    f32x4 t = {bv, bv, bv, bv};
    acc[0][nt] = t; acc[1][nt] = t;
  }
  mm_f32A<LDW>(X + (size_t)row0 * HH, W + (size_t)colw * LDW, acc, lane);
#pragma unroll
  for (int m = 0; m < 2; ++m)
#pragma unroll
    for (int nt = 0; nt < 4; ++nt)
#pragma unroll
      for (int rr = 0; rr < 4; ++rr) {
        int row = row0 + m * 16 + g * 4 + rr;
        out[(size_t)row * HH + colw + nt * 16 + c] = acc[m][nt][rr];
      }
}

// ---------------- phase A (R4-proven): layer-1 of both MLPs, relu, reductions ----------------
__global__ __launch_bounds__(512) void phaseA_kernel(
    const float* __restrict__ e, const float* __restrict__ p_ap,
    const float* __restrict__ p_ue,
    const bf16_t* __restrict__ wu1e, const bf16_t* __restrict__ wa1e,
    float* __restrict__ part, float* __restrict__ R_ap) {
  __shared__ bf16_t ebuf[2][32 * 256];
  const int blk = blockIdx.x;              // 512 blocks
  const int b = blk >> 3, lc = blk & 7;
  const int tid = threadIdx.x, w = tid >> 6, lane = tid & 63;
  const int colw = w * 32, c = lane & 15, g = lane >> 4;
  const int l0 = lc * LGRP;

  bf16x8 wU[2][8], wA[2][8];
#pragma unroll
  for (int nt = 0; nt < 2; ++nt)
#pragma unroll
    for (int ks = 0; ks < 8; ++ks) {
      size_t off = (size_t)(colw + nt * 16 + c) * 512 + ks * 32 + g * 8;
      wU[nt][ks] = *(const bf16x8*)(wu1e + off);
      wA[nt][ks] = *(const bf16x8*)(wa1e + off);
    }

  float pue[2][2][4];
#pragma unroll
  for (int m = 0; m < 2; ++m)
#pragma unroll
    for (int nt = 0; nt < 2; ++nt)
#pragma unroll
      for (int rr = 0; rr < 4; ++rr)
        pue[m][nt][rr] = p_ue[(size_t)(b * KK + m * 16 + g * 4 + rr) * HH + colw + nt * 16 + c];

  f32x4 accU[2][2];
  const f32x4 z4 = {0.f, 0.f, 0.f, 0.f};
#pragma unroll
  for (int m = 0; m < 2; ++m)
#pragma unroll
    for (int nt = 0; nt < 2; ++nt) accU[m][nt] = z4;

  f32x4 rs[4];
  ld_tile(e + (size_t)((b * LL + l0) * KK) * HH, tid, rs);
  wr_tile(ebuf[0], tid, rs);

  for (int li = 0; li < LGRP; ++li) {
    __syncthreads();
    const int l = l0 + li;
    if (li + 1 < LGRP) ld_tile(e + (size_t)((b * LL + l + 1) * KK) * HH, tid, rs);

    f32x4 aU[2][2], aA[2][2];
#pragma unroll
    for (int nt = 0; nt < 2; ++nt) {
      float pa = p_ap[(size_t)(b * LL + l) * HH + colw + nt * 16 + c];
      f32x4 t = {pa, pa, pa, pa};
      aA[0][nt] = t; aA[1][nt] = t;
#pragma unroll
      for (int rr = 0; rr < 4; ++rr) {
        aU[0][nt][rr] = pue[0][nt][rr];
        aU[1][nt][rr] = pue[1][nt][rr];
      }
    }
    const bf16_t* eb = ebuf[li & 1];
    const int swz = (c & 7) << 4;
#pragma unroll
    for (int ks = 0; ks < 8; ++ks) {
      const int kb = (ks * 32 + g * 8) * 2;
      bf16x8 a0 = *(const bf16x8*)((const char*)eb + c * 512 + (kb ^ swz));
      bf16x8 a1 = *(const bf16x8*)((const char*)eb + (16 + c) * 512 + (kb ^ swz));
#pragma unroll
      for (int nt = 0; nt < 2; ++nt) {
        aU[0][nt] = __builtin_amdgcn_mfma_f32_16x16x32_bf16(a0, wU[nt][ks], aU[0][nt], 0, 0, 0);
        aU[1][nt] = __builtin_amdgcn_mfma_f32_16x16x32_bf16(a1, wU[nt][ks], aU[1][nt], 0, 0, 0);
        aA[0][nt] = __builtin_amdgcn_mfma_f32_16x16x32_bf16(a0, wA[nt][ks], aA[0][nt], 0, 0, 0);
        aA[1][nt] = __builtin_amdgcn_mfma_f32_16x16x32_bf16(a1, wA[nt][ks], aA[1][nt], 0, 0, 0);
      }
    }
    __syncthreads();
    if (li + 1 < LGRP) wr_tile(ebuf[(li + 1) & 1], tid, rs);

#pragma unroll
    for (int nt = 0; nt < 2; ++nt) {
      float s = 0.f;
#pragma unroll
      for (int m = 0; m < 2; ++m)
#pragma unroll
        for (int rr = 0; rr < 4; ++rr) s += fmaxf(aU[m][nt][rr], 0.f);
      s += __shfl_xor(s, 16);
      s += __shfl_xor(s, 32);
      if (lane < 16)
        R_ap[(size_t)(b * LL + l) * HH + colw + nt * 16 + lane] = s;
    }
#pragma unroll
    for (int m = 0; m < 2; ++m)
#pragma unroll
      for (int nt = 0; nt < 2; ++nt)
#pragma unroll
        for (int rr = 0; rr < 4; ++rr)
          accU[m][nt][rr] += fmaxf(aA[m][nt][rr], 0.f);
  }

#pragma unroll
  for (int m = 0; m < 2; ++m)
#pragma unroll
    for (int nt = 0; nt < 2; ++nt)
#pragma unroll
      for (int rr = 0; rr < 4; ++rr) {
        int krow = m * 16 + g * 4 + rr;
        part[(size_t)((lc * BB + b) * KK + krow) * HH + colw + nt * 16 + c] = accU[m][nt][rr];
      }
}

// ============ msg: layer-2 message GEMM only -> m_all (bf16, UE rows then AP rows) ============
__global__ __launch_bounds__(256) void msg_kernel(
    const float* __restrict__ part, const float* __restrict__ R_ap,
    const float* __restrict__ a2u_w2, const float* __restrict__ a2u_b2,
    const float* __restrict__ u2a_w2, const float* __restrict__ u2a_b2,
    bf16_t* __restrict__ m_all) {
  const int blk = blockIdx.x;              // 192: 64 UE + 128 AP
  const bool ue = blk < 64;
  const int row0 = ue ? blk * 32 : (blk - 64) * 32;
  const int mrow0 = ue ? row0 : 2048 + row0;
  const int tid = threadIdx.x, w = tid >> 6, lane = tid & 63;
  const int colw = w * 64, c = lane & 15, g = lane >> 4;
  const float* W2 = ue ? a2u_w2 : u2a_w2;
  const float* b2 = ue ? a2u_b2 : u2a_b2;
  const float sc  = ue ? (1.f / 64.f) : (1.f / 32.f);

  f32x4 acc[2][4];
#pragma unroll
  for (int nt = 0; nt < 4; ++nt) {
    float bv = b2[colw + nt * 16 + c];
    f32x4 t = {bv, bv, bv, bv};
    acc[0][nt] = t; acc[1][nt] = t;
  }
  if (ue) mm_partA(part + (size_t)row0 * HH, W2 + (size_t)colw * HH, acc, lane, sc);
  else    mm_f32AB<HH>(R_ap + (size_t)row0 * HH, W2 + (size_t)colw * HH, acc, lane, sc);

#pragma unroll
  for (int m = 0; m < 2; ++m)
#pragma unroll
    for (int nt = 0; nt < 4; ++nt)
#pragma unroll
      for (int rr = 0; rr < 4; ++rr)
        m_all[(size_t)(mrow0 + m * 16 + g * 4 + rr) * HH + colw + nt * 16 + c] =
            (__bf16)acc[m][nt][rr];
}

// ============ gate: one GRU gate per block (576 = 192 row-tiles x 3 gates) ============
__global__ __launch_bounds__(256) void gate_kernel(
    const bf16_t* __restrict__ m_all,
    const float* __restrict__ h_ue, const float* __restrict__ ue_wih,
    const float* __restrict__ ue_bih, const float* __restrict__ ue_whh,
    const float* __restrict__ ue_bhh,
    const float* __restrict__ h_ap, const float* __restrict__ ap_wih,
    const float* __restrict__ ap_bih, const float* __restrict__ ap_whh,
    const float* __restrict__ ap_bhh,
    float* __restrict__ aR, float* __restrict__ aZ,
    float* __restrict__ aNi, float* __restrict__ aNh) {
  const int gate = blockIdx.x % 3, rt = blockIdx.x / 3;
  const bool ue = rt < 64;
  const int row0 = ue ? rt * 32 : (rt - 64) * 32;
  const int mrow0 = ue ? row0 : 2048 + row0;
  const int tid = threadIdx.x, w = tid >> 6, lane = tid & 63;
  const int colw = w * 64, c = lane & 15, g = lane >> 4;
  const float* h   = ue ? h_ue : h_ap;
  const float* wih = ue ? ue_wih : ap_wih;
  const float* whh = ue ? ue_whh : ap_whh;
  const float* bih = ue ? ue_bih : ap_bih;
  const float* bhh = ue ? ue_bhh : ap_bhh;
  const int go = gate * 256;
  const bf16_t* Am = m_all + (size_t)mrow0 * HH;
  const float*  Ah = h + (size_t)row0 * HH;

  if (gate < 2) {
    // aR / aZ = (bih+bhh) + m*Wih_g^T + h*Whh_g^T
    f32x4 acc[2][4];
#pragma unroll
    for (int nt = 0; nt < 4; ++nt) {
      int col = colw + nt * 16 + c;
      float bv = bih[go + col] + bhh[go + col];
      f32x4 t = {bv, bv, bv, bv};
      acc[0][nt] = t; acc[1][nt] = t;
    }
    mm_bf16A_f32B(Am, wih + (size_t)(go + colw) * HH, acc, lane);
    mm_f32AB<HH>(Ah, whh + (size_t)(go + colw) * HH, acc, lane, 1.f);
    float* dst = gate == 0 ? aR : aZ;
#pragma unroll
    for (int m = 0; m < 2; ++m)
#pragma unroll
      for (int nt = 0; nt < 4; ++nt)
#pragma unroll
        for (int rr = 0; rr < 4; ++rr)
          dst[(size_t)(mrow0 + m * 16 + g * 4 + rr) * HH + colw + nt * 16 + c] = acc[m][nt][rr];
  } else {
    // aNi = bih_n + m*Wih_n^T ; aNh = bhh_n + h*Whh_n^T
    f32x4 ai[2][4], ah[2][4];
#pragma unroll
    for (int nt = 0; nt < 4; ++nt) {
      int col = colw + nt * 16 + c;
      float bi = bih[512 + col], bh = bhh[512 + col];
      f32x4 ti = {bi, bi, bi, bi}, th = {bh, bh, bh, bh};
      ai[0][nt] = ti; ai[1][nt] = ti;
      ah[0][nt] = th; ah[1][nt] = th;
    }
    mm_bf16A_f32B(Am, wih + (size_t)(512 + colw) * HH, ai, lane);
    mm_f32AB<HH>(Ah, whh + (size_t)(512 + colw) * HH, ah, lane, 1.f);
#pragma unroll
    for (int m = 0; m < 2; ++m)
#pragma unroll
      for (int nt = 0; nt < 4; ++nt)
#pragma unroll
        for (int rr = 0; rr < 4; ++rr) {
          size_t off = (size_t)(mrow0 + m * 16 + g * 4 + rr) * HH + colw + nt * 16 + c;
          aNi[off] = ai[m][nt][rr];
          aNh[off] = ah[m][nt][rr];
        }
  }
}

// ============ gruew: elementwise GRU combine -> h_new ============
__global__ __launch_bounds__(256) void gruew_kernel(
    const float* __restrict__ aR, const float* __restrict__ aZ,
    const float* __restrict__ aNi, const float* __restrict__ aNh,
    const float* __restrict__ h_ue, const float* __restrict__ h_ap,
    float* __restrict__ hue_new, float* __restrict__ hap_new) {
  int idx = blockIdx.x * 256 + threadIdx.x;      // 393216 threads, 4 f32 each
  int i4 = idx * 4;
  const bool ue = i4 < 524288;
  const float* hp = ue ? h_ue + i4 : h_ap + (i4 - 524288);
  float* op       = ue ? hue_new + i4 : hap_new + (i4 - 524288);
  f32x4 vR = *(const f32x4*)(aR + i4);
  f32x4 vZ = *(const f32x4*)(aZ + i4);
  f32x4 vI = *(const f32x4*)(aNi + i4);
  f32x4 vH = *(const f32x4*)(aNh + i4);
  f32x4 vh = *(const f32x4*)hp;
  f32x4 o;
#pragma unroll
  for (int j = 0; j < 4; ++j) {
    float rg = 1.f / (1.f + __expf(-vR[j]));
    float zg = 1.f / (1.f + __expf(-vZ[j]));
    float t = vI[j] + rg * vH[j];
    t = fminf(fmaxf(t, -15.f), 15.f);
    float ex = __expf(-2.f * t);
    float ng = (1.f - ex) / (1.f + ex);
    o[j] = (1.f - zg) * ng + zg * vh[j];
  }
  *(f32x4*)op = o;
}

// ---------------- phase C (R4-proven): edge update, weights in regs ----------------
__global__ __launch_bounds__(512) void phaseC_kernel(
    const float* __restrict__ e, const float* __restrict__ q_ue,
    const float* __restrict__ q_ap,
    const bf16_t* __restrict__ wed1e, const bf16_t* __restrict__ wed2,
    const float* __restrict__ ed_b2, float* __restrict__ e_new) {
  __shared__ bf16_t ebuf[2][32 * 256];
  __shared__ bf16_t pbuf[32 * 256];
  const int blk = blockIdx.x;              // 512 blocks
  const int b = blk >> 3, lc = blk & 7;
  const int tid = threadIdx.x, w = tid >> 6, lane = tid & 63;
  const int colw = w * 32, c = lane & 15, g = lane >> 4;
  const int l0 = lc * LGRP;

  bf16x8 w1[2][8], w2[2][8];
#pragma unroll
  for (int nt = 0; nt < 2; ++nt)
#pragma unroll
    for (int ks = 0; ks < 8; ++ks) {
      w1[nt][ks] = *(const bf16x8*)(wed1e + (size_t)(colw + nt * 16 + c) * 768 + ks * 32 + g * 8);
      w2[nt][ks] = *(const bf16x8*)(wed2  + (size_t)(colw + nt * 16 + c) * 256 + ks * 32 + g * 8);
    }

  float qU[2][2][4];
#pragma unroll
  for (int m = 0; m < 2; ++m)
#pragma unroll
    for (int nt = 0; nt < 2; ++nt)
#pragma unroll
      for (int rr = 0; rr < 4; ++rr)
        qU[m][nt][rr] = q_ue[(size_t)(b * KK + m * 16 + g * 4 + rr) * HH + colw + nt * 16 + c];
  float b2v[2];
#pragma unroll
  for (int nt = 0; nt < 2; ++nt) b2v[nt] = ed_b2[colw + nt * 16 + c];

  f32x4 rs[4];
  ld_tile(e + (size_t)((b * LL + l0) * KK) * HH, tid, rs);
  wr_tile(ebuf[0], tid, rs);

  for (int li = 0; li < LGRP; ++li) {
    __syncthreads();
    const int l = l0 + li;

    f32x4 a1[2][2];
#pragma unroll
    for (int nt = 0; nt < 2; ++nt) {
      float qa = q_ap[(size_t)(b * LL + l) * HH + colw + nt * 16 + c];
#pragma unroll
      for (int rr = 0; rr < 4; ++rr) {
        a1[0][nt][rr] = qa + qU[0][nt][rr];
        a1[1][nt][rr] = qa + qU[1][nt][rr];
      }
    }
    const bf16_t* eb = ebuf[li & 1];
    const int swz = (c & 7) << 4;
#pragma unroll
    for (int ks = 0; ks < 8; ++ks) {
      const int kb = (ks * 32 + g * 8) * 2;
      bf16x8 a0 = *(const bf16x8*)((const char*)eb + c * 512 + (kb ^ swz));
      bf16x8 a1f = *(const bf16x8*)((const char*)eb + (16 + c) * 512 + (kb ^ swz));
#pragma unroll
      for (int nt = 0; nt < 2; ++nt) {
        a1[0][nt] = __builtin_amdgcn_mfma_f32_16x16x32_bf16(a0,  w1[nt][ks], a1[0][nt], 0, 0, 0);
        a1[1][nt] = __builtin_amdgcn_mfma_f32_16x16x32_bf16(a1f, w1[nt][ks], a1[1][nt], 0, 0, 0);
      }
    }
    if (li + 1 < LGRP) ld_tile(e + (size_t)((b * LL + l + 1) * KK) * HH, tid, rs);

#pragma unroll
    for (int m = 0; m < 2; ++m)
#pragma unroll
      for (int nt = 0; nt < 2; ++nt)
#pragma unroll
        for (int rr = 0; rr < 4; ++rr) {
          int row = m * 16 + g * 4 + rr;
          int col = colw + nt * 16 + c;
          float v = fmaxf(a1[m][nt][rr], 0.f);
          int off = row * 512 + ((col * 2) ^ ((row & 7) << 4));
          *(bf16_t*)((char*)pbuf + off) = (__bf16)v;
        }
    __syncthreads();

    f32x4 a2[2][2];
#pragma unroll
    for (int nt = 0; nt < 2; ++nt) {
      f32x4 t = {b2v[nt], b2v[nt], b2v[nt], b2v[nt]};
      a2[0][nt] = t; a2[1][nt] = t;
    }
#pragma unroll
    for (int ks = 0; ks < 8; ++ks) {
      const int kb = (ks * 32 + g * 8) * 2;
      bf16x8 a0 = *(const bf16x8*)((const char*)pbuf + c * 512 + (kb ^ swz));
      bf16x8 a1f = *(const bf16x8*)((const char*)pbuf + (16 + c) * 512 + (kb ^ swz));
#pragma unroll
      for (int nt = 0; nt < 2; ++nt) {
        a2[0][nt] = __builtin_amdgcn_mfma_f32_16x16x32_bf16(a0,  w2[nt][ks], a2[0][nt], 0, 0, 0);
        a2[1][nt] = __builtin_amdgcn_mfma_f32_16x16x32_bf16(a1f, w2[nt][ks], a2[1][nt], 0, 0, 0);
      }
    }
#pragma unroll
    for (int m = 0; m < 2; ++m)
#pragma unroll
      for (int nt = 0; nt < 2; ++nt)
#pragma unroll
        for (int rr = 0; rr < 4; ++rr) {
          int row = m * 16 + g * 4 + rr;
          int col = colw + nt * 16 + c;
          e_new[(size_t)((b * LL + l) * KK + row) * HH + colw + nt * 16 + c] = a2[m][nt][rr];
        }
    if (li + 1 < LGRP) wr_tile(ebuf[(li + 1) & 1], tid, rs);
  }
}

extern "C" void kernel_launch(void* const* d_in, const int* in_sizes, int n_in,
                              void* d_out, int out_size, void* d_ws, size_t ws_size,
                              hipStream_t stream) {
  const float* h_ue   = (const float*)d_in[0];
  const float* h_ap   = (const float*)d_in[1];
  const float* e      = (const float*)d_in[2];
  const float* a2u_w1 = (const float*)d_in[3];
  const float* a2u_b1 = (const float*)d_in[4];
  const float* a2u_w2 = (const float*)d_in[5];
  const float* a2u_b2 = (const float*)d_in[6];
  const float* u2a_w1 = (const float*)d_in[7];
  const float* u2a_b1 = (const float*)d_in[8];
  const float* u2a_w2 = (const float*)d_in[9];
  const float* u2a_b2 = (const float*)d_in[10];
  const float* ue_wih = (const float*)d_in[11];
  const float* ue_bih = (const float*)d_in[12];
  const float* ue_whh = (const float*)d_in[13];
  const float* ue_bhh = (const float*)d_in[14];
  const float* ap_wih = (const float*)d_in[15];
  const float* ap_bih = (const float*)d_in[16];
  const float* ap_whh = (const float*)d_in[17];
  const float* ap_bhh = (const float*)d_in[18];
  const float* ed_w1  = (const float*)d_in[19];
  const float* ed_b1  = (const float*)d_in[20];
  const float* ed_w2  = (const float*)d_in[21];
  const float* ed_b2  = (const float*)d_in[22];

  // workspace: bf16 weights [0,1MB), then f32 scratch
  bf16_t* wb   = (bf16_t*)d_ws;
  bf16_t* wa1  = wb;                    // a2u_w1 (256x512)
  bf16_t* wu1  = wb + 131072;           // u2a_w1 (256x512)
  bf16_t* wed1 = wb + 262144;           // ed_w1  (256x768)
  bf16_t* wed2 = wb + 458752;           // ed_w2  (256x256)
  float* fbase = (float*)((char*)d_ws + 1048576);
  float* p_ap = fbase;                  // 1048576 f32   (dead after phaseA)
  float* p_ue = p_ap + 1048576;         // 524288        (dead after phaseA)
  float* part = p_ue + 524288;          // 4194304       (dead after msg)
  float* R_ap = part + 4194304;         // 1048576       (dead after msg)
  // gate buffers alias the dead regions above (each 1572864 f32):
  float* aR  = fbase;                   // [0, 1572864)
  float* aZ  = fbase + 1572864;         // [1572864, 3145728)
  float* aNi = fbase + 3145728;         // [3145728, 4718592)
  float* aNh = fbase + 4718592;         // [4718592, 6291456)
  // non-aliased tail:
  bf16_t* m_all = (bf16_t*)(fbase + 6815744);  // 1572864 bf16 (3MB)
  float* q_ue = fbase + 7602176;        // 524288
  float* q_ap = q_ue + 524288;          // 1048576

  float* out      = (float*)d_out;
  float* hue_new  = out;                // 524288
  float* hap_new  = out + 524288;       // 1048576
  float* e_new    = out + 1572864;      // 33554432

  prep_kernel<<<2048, 256, 0, stream>>>(a2u_w1, u2a_w1, ed_w1, ed_w2, wb);
  proj2_kernel<512><<<192, 256, 0, stream>>>(h_ap, wa1, a2u_b1, p_ap, 128,
                                             h_ue, wu1, u2a_b1, p_ue);
  phaseA_kernel<<<512, 512, 0, stream>>>(e, p_ap, p_ue, wu1 + 256, wa1 + 256,
                                         part, R_ap);
  msg_kernel<<<192, 256, 0, stream>>>(part, R_ap, a2u_w2, a2u_b2, u2a_w2, u2a_b2, m_all);
  gate_kernel<<<576, 256, 0, stream>>>(m_all,
                                       h_ue, ue_wih, ue_bih, ue_whh, ue_bhh,
                                       h_ap, ap_wih, ap_bih, ap_whh, ap_bhh,
                                       aR, aZ, aNi, aNh);
  gruew_kernel<<<1536, 256, 0, stream>>>(aR, aZ, aNi, aNh, h_ue, h_ap, hue_new, hap_new);
  proj2_kernel<768><<<192, 256, 0, stream>>>(hue_new, wed1, ed_b1, q_ue, 64,
                                             hap_new, wed1 + 256, nullptr, q_ap);
  phaseC_kernel<<<512, 512, 0, stream>>>(e, q_ue, q_ap, wed1 + 512, wed2, ed_b2, e_new);
}

// Round 9
// 240.998 us; speedup vs baseline: 1.1921x; 1.1921x over previous
//
#include <hip/hip_runtime.h>

#define HH 256   // H
#define BB 64    // B
#define KK 32    // K
#define LL 64    // L
#define LGRP 8   // l's per edge-kernel block

typedef __bf16 bf16_t;
typedef __attribute__((ext_vector_type(8))) __bf16 bf16x8;
typedef __attribute__((ext_vector_type(4))) float f32x4;

// ---- load 8 contiguous f32, convert to bf16x8 ----
__device__ __forceinline__ bf16x8 ld_a8(const float* __restrict__ p) {
  const f32x4* q = (const f32x4*)p;
  f32x4 a = q[0], b = q[1];
  bf16x8 r;
  r[0] = (__bf16)a[0]; r[1] = (__bf16)a[1]; r[2] = (__bf16)a[2]; r[3] = (__bf16)a[3];
  r[4] = (__bf16)b[0]; r[5] = (__bf16)b[1]; r[6] = (__bf16)b[2]; r[7] = (__bf16)b[3];
  return r;
}

// ---- e-tile staging (512 threads): 16 f32/thread -> regs -> swizzled bf16 LDS ----
__device__ __forceinline__ void ld_tile(const float* __restrict__ E, int tid, f32x4 r[4]) {
  const f32x4* q = (const f32x4*)(E + tid * 16);
  r[0] = q[0]; r[1] = q[1]; r[2] = q[2]; r[3] = q[3];
}
// non-temporal variant (phaseC: last reader of e)
__device__ __forceinline__ void ld_tile_nt(const float* __restrict__ E, int tid, f32x4 r[4]) {
  const f32x4* q = (const f32x4*)(E + tid * 16);
  r[0] = __builtin_nontemporal_load(q);
  r[1] = __builtin_nontemporal_load(q + 1);
  r[2] = __builtin_nontemporal_load(q + 2);
  r[3] = __builtin_nontemporal_load(q + 3);
}
__device__ __forceinline__ void wr_tile(bf16_t* buf, int tid, const f32x4 r[4]) {
  int row = tid >> 4;
  int colb = (tid & 15) * 32;
  bf16x8 v0, v1;
  v0[0] = (__bf16)r[0][0]; v0[1] = (__bf16)r[0][1]; v0[2] = (__bf16)r[0][2]; v0[3] = (__bf16)r[0][3];
  v0[4] = (__bf16)r[1][0]; v0[5] = (__bf16)r[1][1]; v0[6] = (__bf16)r[1][2]; v0[7] = (__bf16)r[1][3];
  v1[0] = (__bf16)r[2][0]; v1[1] = (__bf16)r[2][1]; v1[2] = (__bf16)r[2][2]; v1[3] = (__bf16)r[2][3];
  v1[4] = (__bf16)r[3][0]; v1[5] = (__bf16)r[3][1]; v1[6] = (__bf16)r[3][2]; v1[7] = (__bf16)r[3][3];
  int swz = (row & 7) << 4;
  *(bf16x8*)((char*)buf + row * 512 + (colb ^ swz)) = v0;
  *(bf16x8*)((char*)buf + row * 512 + ((colb + 16) ^ swz)) = v1;
}

// acc[2][4] += A(32x256 f32 global)*B(bf16 row-major)^T  (4-wave kernels, 64-col wave)
template<int LDB>
__device__ __forceinline__ void mm_f32A(const float* __restrict__ A,
                                        const bf16_t* __restrict__ B,
                                        f32x4 acc[2][4], int lane) {
  const int c = lane & 15, g = lane >> 4;
#pragma unroll
  for (int ks = 0; ks < 8; ++ks) {
    const int ko = ks * 32 + g * 8;
    bf16x8 a0 = ld_a8(A + (size_t)c * HH + ko);
    bf16x8 a1 = ld_a8(A + (size_t)(16 + c) * HH + ko);
#pragma unroll
    for (int nt = 0; nt < 4; ++nt) {
      bf16x8 bb = *(const bf16x8*)(B + (size_t)(nt * 16 + c) * LDB + ko);
      acc[0][nt] = __builtin_amdgcn_mfma_f32_16x16x32_bf16(a0, bb, acc[0][nt], 0, 0, 0);
      acc[1][nt] = __builtin_amdgcn_mfma_f32_16x16x32_bf16(a1, bb, acc[1][nt], 0, 0, 0);
    }
  }
}

// ---------------- prep: all weights f32->bf16 (layer-2 msg weights pre-scaled) ----------------
__global__ __launch_bounds__(256) void prep_kernel(
    const float* w0, const float* w1, const float* w2, const float* w3,
    const float* w4, const float* w5, const float* w6, const float* w7,
    const float* w8, const float* w9, bf16_t* wb) {
  int i = blockIdx.x * 256 + threadIdx.x;
  const float* s; int o; float sc = 1.f;
  if      (i < 131072)  { s = w0; o = i; }
  else if (i < 196608)  { s = w1; o = i - 131072; sc = 1.f / 64.f; }   // a2u_w2 / L
  else if (i < 327680)  { s = w2; o = i - 196608; }
  else if (i < 393216)  { s = w3; o = i - 327680; sc = 1.f / 32.f; }   // u2a_w2 / K
  else if (i < 589824)  { s = w4; o = i - 393216; }
  else if (i < 786432)  { s = w5; o = i - 589824; }
  else if (i < 983040)  { s = w6; o = i - 786432; }
  else if (i < 1179648) { s = w7; o = i - 983040; }
  else if (i < 1376256) { s = w8; o = i - 1179648; }
  else                  { s = w9; o = i - 1376256; }
  wb[i] = (__bf16)(s[o] * sc);
}

// ---------------- fused pair of projections: out = X*W^T + bias ----------------
template<int LDW>
__global__ __launch_bounds__(256) void proj2_kernel(
    const float* __restrict__ X0, const bf16_t* __restrict__ W0,
    const float* __restrict__ b0, float* __restrict__ out0, int n0,
    const float* __restrict__ X1, const bf16_t* __restrict__ W1,
    const float* __restrict__ b1, float* __restrict__ out1) {
  const int blk = blockIdx.x;
  const float* X; const bf16_t* W; const float* bias; float* out; int row0;
  if (blk < n0) { X = X0; W = W0; bias = b0; out = out0; row0 = blk * 32; }
  else          { X = X1; W = W1; bias = b1; out = out1; row0 = (blk - n0) * 32; }
  const int tid = threadIdx.x, w = tid >> 6, lane = tid & 63;
  const int colw = w * 64, c = lane & 15, g = lane >> 4;
  f32x4 acc[2][4];
#pragma unroll
  for (int nt = 0; nt < 4; ++nt) {
    float bv = bias ? bias[colw + nt * 16 + c] : 0.f;
    f32x4 t = {bv, bv, bv, bv};
    acc[0][nt] = t; acc[1][nt] = t;
  }
  mm_f32A<LDW>(X + (size_t)row0 * HH, W + (size_t)colw * LDW, acc, lane);
#pragma unroll
  for (int m = 0; m < 2; ++m)
#pragma unroll
    for (int nt = 0; nt < 4; ++nt)
#pragma unroll
      for (int rr = 0; rr < 4; ++rr) {
        int row = row0 + m * 16 + g * 4 + rr;
        out[(size_t)row * HH + colw + nt * 16 + c] = acc[m][nt][rr];
      }
}

// ---------------- phase A: layer-1 of both message MLPs, relu, reductions ----------------
// 512 threads = 8 waves; wave owns 32 output cols; bf16 weights register-resident.
__global__ __launch_bounds__(512) void phaseA_kernel(
    const float* __restrict__ e, const float* __restrict__ p_ap,
    const float* __restrict__ p_ue,
    const bf16_t* __restrict__ wu1e, const bf16_t* __restrict__ wa1e,
    float* __restrict__ part, float* __restrict__ R_ap) {
  __shared__ bf16_t ebuf[2][32 * 256];
  const int blk = blockIdx.x;              // 512 blocks
  const int b = blk >> 3, lc = blk & 7;
  const int tid = threadIdx.x, w = tid >> 6, lane = tid & 63;
  const int colw = w * 32, c = lane & 15, g = lane >> 4;
  const int l0 = lc * LGRP;

  bf16x8 wU[2][8], wA[2][8];
#pragma unroll
  for (int nt = 0; nt < 2; ++nt)
#pragma unroll
    for (int ks = 0; ks < 8; ++ks) {
      size_t off = (size_t)(colw + nt * 16 + c) * 512 + ks * 32 + g * 8;
      wU[nt][ks] = *(const bf16x8*)(wu1e + off);
      wA[nt][ks] = *(const bf16x8*)(wa1e + off);
    }

  float pue[2][2][4];
#pragma unroll
  for (int m = 0; m < 2; ++m)
#pragma unroll
    for (int nt = 0; nt < 2; ++nt)
#pragma unroll
      for (int rr = 0; rr < 4; ++rr)
        pue[m][nt][rr] = p_ue[(size_t)(b * KK + m * 16 + g * 4 + rr) * HH + colw + nt * 16 + c];

  f32x4 accU[2][2];
  const f32x4 z4 = {0.f, 0.f, 0.f, 0.f};
#pragma unroll
  for (int m = 0; m < 2; ++m)
#pragma unroll
    for (int nt = 0; nt < 2; ++nt) accU[m][nt] = z4;

  f32x4 rs[4];
  ld_tile(e + (size_t)((b * LL + l0) * KK) * HH, tid, rs);
  wr_tile(ebuf[0], tid, rs);

  for (int li = 0; li < LGRP; ++li) {
    __syncthreads();
    const int l = l0 + li;
    if (li + 1 < LGRP) ld_tile(e + (size_t)((b * LL + l + 1) * KK) * HH, tid, rs);

    f32x4 aU[2][2], aA[2][2];
#pragma unroll
    for (int nt = 0; nt < 2; ++nt) {
      float pa = p_ap[(size_t)(b * LL + l) * HH + colw + nt * 16 + c];
      f32x4 t = {pa, pa, pa, pa};
      aA[0][nt] = t; aA[1][nt] = t;
#pragma unroll
      for (int rr = 0; rr < 4; ++rr) {
        aU[0][nt][rr] = pue[0][nt][rr];
        aU[1][nt][rr] = pue[1][nt][rr];
      }
    }
    const bf16_t* eb = ebuf[li & 1];
    const int swz = (c & 7) << 4;
#pragma unroll
    for (int ks = 0; ks < 8; ++ks) {
      const int kb = (ks * 32 + g * 8) * 2;
      bf16x8 a0 = *(const bf16x8*)((const char*)eb + c * 512 + (kb ^ swz));
      bf16x8 a1 = *(const bf16x8*)((const char*)eb + (16 + c) * 512 + (kb ^ swz));
#pragma unroll
      for (int nt = 0; nt < 2; ++nt) {
        aU[0][nt] = __builtin_amdgcn_mfma_f32_16x16x32_bf16(a0, wU[nt][ks], aU[0][nt], 0, 0, 0);
        aU[1][nt] = __builtin_amdgcn_mfma_f32_16x16x32_bf16(a1, wU[nt][ks], aU[1][nt], 0, 0, 0);
        aA[0][nt] = __builtin_amdgcn_mfma_f32_16x16x32_bf16(a0, wA[nt][ks], aA[0][nt], 0, 0, 0);
        aA[1][nt] = __builtin_amdgcn_mfma_f32_16x16x32_bf16(a1, wA[nt][ks], aA[1][nt], 0, 0, 0);
      }
    }
    __syncthreads();
    if (li + 1 < LGRP) wr_tile(ebuf[(li + 1) & 1], tid, rs);

    // u2a: relu + k-reduce -> R_ap[b,l,:]  (no bias; /K folded in wu2s at m-GEMM)
#pragma unroll
    for (int nt = 0; nt < 2; ++nt) {
      float s = 0.f;
#pragma unroll
      for (int m = 0; m < 2; ++m)
#pragma unroll
        for (int rr = 0; rr < 4; ++rr) s += fmaxf(aU[m][nt][rr], 0.f);
      s += __shfl_xor(s, 16);
      s += __shfl_xor(s, 32);
      if (lane < 16)
        R_ap[(size_t)(b * LL + l) * HH + colw + nt * 16 + lane] = s;
    }
    // a2u: relu accumulate over l
#pragma unroll
    for (int m = 0; m < 2; ++m)
#pragma unroll
      for (int nt = 0; nt < 2; ++nt)
#pragma unroll
        for (int rr = 0; rr < 4; ++rr)
          accU[m][nt][rr] += fmaxf(aA[m][nt][rr], 0.f);
  }

#pragma unroll
  for (int m = 0; m < 2; ++m)
#pragma unroll
    for (int nt = 0; nt < 2; ++nt)
#pragma unroll
      for (int rr = 0; rr < 4; ++rr) {
        int krow = m * 16 + g * 4 + rr;
        part[(size_t)((lc * BB + b) * KK + krow) * HH + colw + nt * 16 + c] = accU[m][nt][rr];
      }
}

// ---------------- reduce partials -> R_ue (Σ_l relu; /L folded in wa2s) ----------------
__global__ __launch_bounds__(256) void reduce_kernel(
    const float* __restrict__ part, float* __restrict__ R_ue) {
  int i = blockIdx.x * 256 + threadIdx.x;
  float s = 0.f;
#pragma unroll
  for (int lc = 0; lc < 8; ++lc) s += part[(size_t)lc * 524288 + i];
  R_ue[i] = s;
}

// ---------------- merged GRUs (bf16 weights) ----------------
__global__ __launch_bounds__(256) void gru_kernel(
    const float* __restrict__ m_ue, const float* __restrict__ h_ue,
    const bf16_t* __restrict__ wih_ue, const bf16_t* __restrict__ whh_ue,
    const float* __restrict__ ue_bih, const float* __restrict__ ue_bhh,
    float* __restrict__ hue_new,
    const float* __restrict__ m_ap, const float* __restrict__ h_ap,
    const bf16_t* __restrict__ wih_ap, const bf16_t* __restrict__ whh_ap,
    const float* __restrict__ ap_bih, const float* __restrict__ ap_bhh,
    float* __restrict__ hap_new) {
  const int blk = blockIdx.x;
  const float *x, *h, *bih, *bhh; const bf16_t *wih, *whh; float* hout; int row0;
  if (blk < 64) { x = m_ue; h = h_ue; wih = wih_ue; whh = whh_ue;
                  bih = ue_bih; bhh = ue_bhh; hout = hue_new; row0 = blk * 32; }
  else          { x = m_ap; h = h_ap; wih = wih_ap; whh = whh_ap;
                  bih = ap_bih; bhh = ap_bhh; hout = hap_new; row0 = (blk - 64) * 32; }
  const int tid = threadIdx.x, w = tid >> 6, lane = tid & 63;
  const int colw = w * 64, c = lane & 15, g = lane >> 4;
  f32x4 aR[2][4], aZ[2][4], aN[2][4], aHN[2][4];
#pragma unroll
  for (int nt = 0; nt < 4; ++nt) {
    int col = colw + nt * 16 + c;
    float vR = bih[col] + bhh[col];
    float vZ = bih[256 + col] + bhh[256 + col];
    float vN = bih[512 + col];
    float vH = bhh[512 + col];
    f32x4 tR = {vR, vR, vR, vR}, tZ = {vZ, vZ, vZ, vZ};
    f32x4 tN = {vN, vN, vN, vN}, tH = {vH, vH, vH, vH};
    aR[0][nt] = tR; aR[1][nt] = tR;
    aZ[0][nt] = tZ; aZ[1][nt] = tZ;
    aN[0][nt] = tN; aN[1][nt] = tN;
    aHN[0][nt] = tH; aHN[1][nt] = tH;
  }
  const float* X = x + (size_t)row0 * HH;
  const float* Hp = h + (size_t)row0 * HH;
  mm_f32A<256>(X,  wih + (size_t)(0   + colw) * 256, aR, lane);
  mm_f32A<256>(Hp, whh + (size_t)(0   + colw) * 256, aR, lane);
  mm_f32A<256>(X,  wih + (size_t)(256 + colw) * 256, aZ, lane);
  mm_f32A<256>(Hp, whh + (size_t)(256 + colw) * 256, aZ, lane);
  mm_f32A<256>(X,  wih + (size_t)(512 + colw) * 256, aN, lane);
  mm_f32A<256>(Hp, whh + (size_t)(512 + colw) * 256, aHN, lane);
#pragma unroll
  for (int m = 0; m < 2; ++m)
#pragma unroll
    for (int nt = 0; nt < 4; ++nt)
#pragma unroll
      for (int rr = 0; rr < 4; ++rr) {
        int row = row0 + m * 16 + g * 4 + rr;
        int col = colw + nt * 16 + c;
        float rg = 1.f / (1.f + __expf(-aR[m][nt][rr]));
        float zg = 1.f / (1.f + __expf(-aZ[m][nt][rr]));
        float t = aN[m][nt][rr] + rg * aHN[m][nt][rr];
        t = fminf(fmaxf(t, -15.f), 15.f);
        float ex = __expf(-2.f * t);
        float ng = (1.f - ex) / (1.f + ex);
        float ho = h[(size_t)row * HH + col];
        hout[(size_t)row * HH + col] = (1.f - zg) * ng + zg * ho;
      }
}

// ---------------- phase C: edge update (weights in regs, 8 l's per block) ----------------
__global__ __launch_bounds__(512) void phaseC_kernel(
    const float* __restrict__ e, const float* __restrict__ q_ue,
    const float* __restrict__ q_ap,
    const bf16_t* __restrict__ wed1e, const bf16_t* __restrict__ wed2,
    const float* __restrict__ ed_b2, float* __restrict__ e_new) {
  __shared__ bf16_t ebuf[2][32 * 256];
  __shared__ bf16_t pbuf[32 * 256];
  const int blk = blockIdx.x;              // 512 blocks
  const int b = blk >> 3, lc = blk & 7;
  const int tid = threadIdx.x, w = tid >> 6, lane = tid & 63;
  const int colw = w * 32, c = lane & 15, g = lane >> 4;
  const int l0 = lc * LGRP;

  bf16x8 w1[2][8], w2[2][8];
#pragma unroll
  for (int nt = 0; nt < 2; ++nt)
#pragma unroll
    for (int ks = 0; ks < 8; ++ks) {
      w1[nt][ks] = *(const bf16x8*)(wed1e + (size_t)(colw + nt * 16 + c) * 768 + ks * 32 + g * 8);
      w2[nt][ks] = *(const bf16x8*)(wed2  + (size_t)(colw + nt * 16 + c) * 256 + ks * 32 + g * 8);
    }

  float qU[2][2][4];
#pragma unroll
  for (int m = 0; m < 2; ++m)
#pragma unroll
    for (int nt = 0; nt < 2; ++nt)
#pragma unroll
      for (int rr = 0; rr < 4; ++rr)
        qU[m][nt][rr] = q_ue[(size_t)(b * KK + m * 16 + g * 4 + rr) * HH + colw + nt * 16 + c];
  float b2v[2];
#pragma unroll
  for (int nt = 0; nt < 2; ++nt) b2v[nt] = ed_b2[colw + nt * 16 + c];

  f32x4 rs[4];
  ld_tile_nt(e + (size_t)((b * LL + l0) * KK) * HH, tid, rs);
  wr_tile(ebuf[0], tid, rs);

  for (int li = 0; li < LGRP; ++li) {
    __syncthreads();                       // ebuf[li&1] visible; prev pbuf readers done
    const int l = l0 + li;

    f32x4 a1[2][2];
#pragma unroll
    for (int nt = 0; nt < 2; ++nt) {
      float qa = q_ap[(size_t)(b * LL + l) * HH + colw + nt * 16 + c];
#pragma unroll
      for (int rr = 0; rr < 4; ++rr) {
        a1[0][nt][rr] = qa + qU[0][nt][rr];
        a1[1][nt][rr] = qa + qU[1][nt][rr];
      }
    }
    const bf16_t* eb = ebuf[li & 1];
    const int swz = (c & 7) << 4;
#pragma unroll
    for (int ks = 0; ks < 8; ++ks) {
      const int kb = (ks * 32 + g * 8) * 2;
      bf16x8 a0 = *(const bf16x8*)((const char*)eb + c * 512 + (kb ^ swz));
      bf16x8 a1f = *(const bf16x8*)((const char*)eb + (16 + c) * 512 + (kb ^ swz));
#pragma unroll
      for (int nt = 0; nt < 2; ++nt) {
        a1[0][nt] = __builtin_amdgcn_mfma_f32_16x16x32_bf16(a0,  w1[nt][ks], a1[0][nt], 0, 0, 0);
        a1[1][nt] = __builtin_amdgcn_mfma_f32_16x16x32_bf16(a1f, w1[nt][ks], a1[1][nt], 0, 0, 0);
      }
    }
    if (li + 1 < LGRP) ld_tile_nt(e + (size_t)((b * LL + l + 1) * KK) * HH, tid, rs);

    // relu -> pbuf (this wave's 32-col slice)
#pragma unroll
    for (int m = 0; m < 2; ++m)
#pragma unroll
      for (int nt = 0; nt < 2; ++nt)
#pragma unroll
        for (int rr = 0; rr < 4; ++rr) {
          int row = m * 16 + g * 4 + rr;
          int col = colw + nt * 16 + c;
          float v = fmaxf(a1[m][nt][rr], 0.f);
          int off = row * 512 + ((col * 2) ^ ((row & 7) << 4));
          *(bf16_t*)((char*)pbuf + off) = (__bf16)v;
        }
    __syncthreads();                       // pbuf visible

    f32x4 a2[2][2];
#pragma unroll
    for (int nt = 0; nt < 2; ++nt) {
      f32x4 t = {b2v[nt], b2v[nt], b2v[nt], b2v[nt]};
      a2[0][nt] = t; a2[1][nt] = t;
    }
#pragma unroll
    for (int ks = 0; ks < 8; ++ks) {
      const int kb = (ks * 32 + g * 8) * 2;
      bf16x8 a0 = *(const bf16x8*)((const char*)pbuf + c * 512 + (kb ^ swz));
      bf16x8 a1f = *(const bf16x8*)((const char*)pbuf + (16 + c) * 512 + (kb ^ swz));
#pragma unroll
      for (int nt = 0; nt < 2; ++nt) {
        a2[0][nt] = __builtin_amdgcn_mfma_f32_16x16x32_bf16(a0,  w2[nt][ks], a2[0][nt], 0, 0, 0);
        a2[1][nt] = __builtin_amdgcn_mfma_f32_16x16x32_bf16(a1f, w2[nt][ks], a2[1][nt], 0, 0, 0);
      }
    }
#pragma unroll
    for (int m = 0; m < 2; ++m)
#pragma unroll
      for (int nt = 0; nt < 2; ++nt)
#pragma unroll
        for (int rr = 0; rr < 4; ++rr) {
          int row = m * 16 + g * 4 + rr;
          int col = colw + nt * 16 + c;
          __builtin_nontemporal_store(
              a2[m][nt][rr],
              &e_new[(size_t)((b * LL + l) * KK + row) * HH + col]);
        }
    if (li + 1 < LGRP) wr_tile(ebuf[(li + 1) & 1], tid, rs);
  }
}

extern "C" void kernel_launch(void* const* d_in, const int* in_sizes, int n_in,
                              void* d_out, int out_size, void* d_ws, size_t ws_size,
                              hipStream_t stream) {
  const float* h_ue   = (const float*)d_in[0];
  const float* h_ap   = (const float*)d_in[1];
  const float* e      = (const float*)d_in[2];
  const float* a2u_w1 = (const float*)d_in[3];
  const float* a2u_b1 = (const float*)d_in[4];
  const float* a2u_w2 = (const float*)d_in[5];
  const float* a2u_b2 = (const float*)d_in[6];
  const float* u2a_w1 = (const float*)d_in[7];
  const float* u2a_b1 = (const float*)d_in[8];
  const float* u2a_w2 = (const float*)d_in[9];
  const float* u2a_b2 = (const float*)d_in[10];
  const float* ue_wih = (const float*)d_in[11];
  const float* ue_bih = (const float*)d_in[12];
  const float* ue_whh = (const float*)d_in[13];
  const float* ue_bhh = (const float*)d_in[14];
  const float* ap_wih = (const float*)d_in[15];
  const float* ap_bih = (const float*)d_in[16];
  const float* ap_whh = (const float*)d_in[17];
  const float* ap_bhh = (const float*)d_in[18];
  const float* ed_w1  = (const float*)d_in[19];
  const float* ed_b1  = (const float*)d_in[20];
  const float* ed_w2  = (const float*)d_in[21];
  const float* ed_b2  = (const float*)d_in[22];

  // workspace layout (bf16 weights, then f32 scratch) — R4-proven
  bf16_t* wb      = (bf16_t*)d_ws;
  bf16_t* wa1     = wb;                 // a2u_w1 (256x512)
  bf16_t* wa2s    = wa1 + 131072;       // a2u_w2 / 64
  bf16_t* wu1     = wa2s + 65536;       // u2a_w1 (256x512)
  bf16_t* wu2s    = wu1 + 131072;       // u2a_w2 / 32
  bf16_t* wih_ue  = wu2s + 65536;
  bf16_t* whh_ue  = wih_ue + 196608;
  bf16_t* wih_ap  = whh_ue + 196608;
  bf16_t* whh_ap  = wih_ap + 196608;
  bf16_t* wed1    = whh_ap + 196608;    // ed_w1 (256x768)
  bf16_t* wed2    = wed1 + 196608;      // ed_w2 (256x256)
  float* fbase = (float*)((char*)d_ws + 2883584);
  float* m_ue = fbase;                  // 524288
  float* m_ap = m_ue + 524288;          // 1048576
  float* p_ap = m_ap + 1048576;         // 1048576
  float* p_ue = p_ap + 1048576;         // 524288
  float* q_ue = p_ue + 524288;          // 524288  (aliased: R_ue before GRU)
  float* q_ap = q_ue + 524288;          // 1048576 (aliased: R_ap before GRU)
  float* part = q_ap + 1048576;         // 8 * 524288
  float* R_ue = q_ue;                   // dead before q_ue written
  float* R_ap = q_ap;                   // dead before q_ap written

  float* out      = (float*)d_out;
  float* hue_new  = out;                // 524288
  float* hap_new  = out + 524288;       // 1048576
  float* e_new    = out + 1572864;      // 33554432

  prep_kernel<<<5632, 256, 0, stream>>>(a2u_w1, a2u_w2, u2a_w1, u2a_w2,
                                        ue_wih, ue_whh, ap_wih, ap_whh,
                                        ed_w1, ed_w2, wb);
  // p_ap = h_ap*Wa1_h^T + b1 ; p_ue = h_ue*Wu1_h^T + b1
  proj2_kernel<512><<<192, 256, 0, stream>>>(h_ap, wa1, a2u_b1, p_ap, 128,
                                             h_ue, wu1, u2a_b1, p_ue);
  phaseA_kernel<<<512, 512, 0, stream>>>(e, p_ap, p_ue, wu1 + 256, wa1 + 256,
                                         part, R_ap);
  reduce_kernel<<<2048, 256, 0, stream>>>(part, R_ue);
  // m_ue = R_ue*(Wa2/L)^T + b2 ; m_ap = R_ap*(Wu2/K)^T + b2
  proj2_kernel<256><<<192, 256, 0, stream>>>(R_ue, wa2s, a2u_b2, m_ue, 64,
                                             R_ap, wu2s, u2a_b2, m_ap);
  gru_kernel<<<192, 256, 0, stream>>>(m_ue, h_ue, wih_ue, whh_ue, ue_bih, ue_bhh, hue_new,
                                      m_ap, h_ap, wih_ap, whh_ap, ap_bih, ap_bhh, hap_new);
  // q_ue = hue_new*Wed1[:, :H]^T + ed_b1 ; q_ap = hap_new*Wed1[:, H:2H]^T
  proj2_kernel<768><<<192, 256, 0, stream>>>(hue_new, wed1, ed_b1, q_ue, 64,
                                             hap_new, wed1 + 256, nullptr, q_ap);
  phaseC_kernel<<<512, 512, 0, stream>>>(e, q_ue, q_ap, wed1 + 512, wed2, ed_b2, e_new);
}

// Round 10
// 215.779 us; speedup vs baseline: 1.3315x; 1.1169x over previous
//
#include <hip/hip_runtime.h>

#define HH 256   // H
#define BB 64    // B
#define KK 32    // K
#define LL 64    // L
#define LGRP 8   // l's per edge-kernel block

typedef __bf16 bf16_t;
typedef __attribute__((ext_vector_type(8))) __bf16 bf16x8;
typedef __attribute__((ext_vector_type(4))) float f32x4;

// ---- load 8 contiguous f32, convert to bf16x8 ----
__device__ __forceinline__ bf16x8 ld_a8(const float* __restrict__ p) {
  const f32x4* q = (const f32x4*)p;
  f32x4 a = q[0], b = q[1];
  bf16x8 r;
  r[0] = (__bf16)a[0]; r[1] = (__bf16)a[1]; r[2] = (__bf16)a[2]; r[3] = (__bf16)a[3];
  r[4] = (__bf16)b[0]; r[5] = (__bf16)b[1]; r[6] = (__bf16)b[2]; r[7] = (__bf16)b[3];
  return r;
}

// ---- e-tile staging (512 threads): 16 f32/thread -> regs -> swizzled bf16 LDS ----
__device__ __forceinline__ void ld_tile(const float* __restrict__ E, int tid, f32x4 r[4]) {
  const f32x4* q = (const f32x4*)(E + tid * 16);
  r[0] = q[0]; r[1] = q[1]; r[2] = q[2]; r[3] = q[3];
}
__device__ __forceinline__ void wr_tile(bf16_t* buf, int tid, const f32x4 r[4]) {
  int row = tid >> 4;
  int colb = (tid & 15) * 32;
  bf16x8 v0, v1;
  v0[0] = (__bf16)r[0][0]; v0[1] = (__bf16)r[0][1]; v0[2] = (__bf16)r[0][2]; v0[3] = (__bf16)r[0][3];
  v0[4] = (__bf16)r[1][0]; v0[5] = (__bf16)r[1][1]; v0[6] = (__bf16)r[1][2]; v0[7] = (__bf16)r[1][3];
  v1[0] = (__bf16)r[2][0]; v1[1] = (__bf16)r[2][1]; v1[2] = (__bf16)r[2][2]; v1[3] = (__bf16)r[2][3];
  v1[4] = (__bf16)r[3][0]; v1[5] = (__bf16)r[3][1]; v1[6] = (__bf16)r[3][2]; v1[7] = (__bf16)r[3][3];
  int swz = (row & 7) << 4;
  *(bf16x8*)((char*)buf + row * 512 + (colb ^ swz)) = v0;
  *(bf16x8*)((char*)buf + row * 512 + ((colb + 16) ^ swz)) = v1;
}

// acc[2][4] += A(32x256 f32 global)*B(bf16 row-major)^T  (4-wave kernels, 64-col wave)
template<int LDB>
__device__ __forceinline__ void mm_f32A(const float* __restrict__ A,
                                        const bf16_t* __restrict__ B,
                                        f32x4 acc[2][4], int lane) {
  const int c = lane & 15, g = lane >> 4;
#pragma unroll
  for (int ks = 0; ks < 8; ++ks) {
    const int ko = ks * 32 + g * 8;
    bf16x8 a0 = ld_a8(A + (size_t)c * HH + ko);
    bf16x8 a1 = ld_a8(A + (size_t)(16 + c) * HH + ko);
#pragma unroll
    for (int nt = 0; nt < 4; ++nt) {
      bf16x8 bb = *(const bf16x8*)(B + (size_t)(nt * 16 + c) * LDB + ko);
      acc[0][nt] = __builtin_amdgcn_mfma_f32_16x16x32_bf16(a0, bb, acc[0][nt], 0, 0, 0);
      acc[1][nt] = __builtin_amdgcn_mfma_f32_16x16x32_bf16(a1, bb, acc[1][nt], 0, 0, 0);
    }
  }
}

// ---------------- prep: all weights f32->bf16 (layer-2 msg weights pre-scaled) ----------------
__global__ __launch_bounds__(256) void prep_kernel(
    const float* w0, const float* w1, const float* w2, const float* w3,
    const float* w4, const float* w5, const float* w6, const float* w7,
    const float* w8, const float* w9, bf16_t* wb) {
  int i = blockIdx.x * 256 + threadIdx.x;
  const float* s; int o; float sc = 1.f;
  if      (i < 131072)  { s = w0; o = i; }
  else if (i < 196608)  { s = w1; o = i - 131072; sc = 1.f / 64.f; }   // a2u_w2 / L
  else if (i < 327680)  { s = w2; o = i - 196608; }
  else if (i < 393216)  { s = w3; o = i - 327680; sc = 1.f / 32.f; }   // u2a_w2 / K
  else if (i < 589824)  { s = w4; o = i - 393216; }
  else if (i < 786432)  { s = w5; o = i - 589824; }
  else if (i < 983040)  { s = w6; o = i - 786432; }
  else if (i < 1179648) { s = w7; o = i - 983040; }
  else if (i < 1376256) { s = w8; o = i - 1179648; }
  else                  { s = w9; o = i - 1376256; }
  wb[i] = (__bf16)(s[o] * sc);
}

// ---------------- fused pair of projections: out = X*W^T + bias ----------------
template<int LDW>
__global__ __launch_bounds__(256) void proj2_kernel(
    const float* __restrict__ X0, const bf16_t* __restrict__ W0,
    const float* __restrict__ b0, float* __restrict__ out0, int n0,
    const float* __restrict__ X1, const bf16_t* __restrict__ W1,
    const float* __restrict__ b1, float* __restrict__ out1) {
  const int blk = blockIdx.x;
  const float* X; const bf16_t* W; const float* bias; float* out; int row0;
  if (blk < n0) { X = X0; W = W0; bias = b0; out = out0; row0 = blk * 32; }
  else          { X = X1; W = W1; bias = b1; out = out1; row0 = (blk - n0) * 32; }
  const int tid = threadIdx.x, w = tid >> 6, lane = tid & 63;
  const int colw = w * 64, c = lane & 15, g = lane >> 4;
  f32x4 acc[2][4];
#pragma unroll
  for (int nt = 0; nt < 4; ++nt) {
    float bv = bias ? bias[colw + nt * 16 + c] : 0.f;
    f32x4 t = {bv, bv, bv, bv};
    acc[0][nt] = t; acc[1][nt] = t;
  }
  mm_f32A<LDW>(X + (size_t)row0 * HH, W + (size_t)colw * LDW, acc, lane);
#pragma unroll
  for (int m = 0; m < 2; ++m)
#pragma unroll
    for (int nt = 0; nt < 4; ++nt)
#pragma unroll
      for (int rr = 0; rr < 4; ++rr) {
        int row = row0 + m * 16 + g * 4 + rr;
        out[(size_t)row * HH + colw + nt * 16 + c] = acc[m][nt][rr];
      }
}

// ---------------- phase A: layer-1 of both message MLPs, relu, reductions ----------------
// 512 threads = 8 waves; wave owns 32 output cols; bf16 weights register-resident.
// ONE barrier per l-iteration: wr_tile(li) targets ebuf[(li+1)&1], whose last readers
// (iteration li-1) necessarily passed this iteration's barrier before the write.
__global__ __launch_bounds__(512) void phaseA_kernel(
    const float* __restrict__ e, const float* __restrict__ p_ap,
    const float* __restrict__ p_ue,
    const bf16_t* __restrict__ wu1e, const bf16_t* __restrict__ wa1e,
    float* __restrict__ part, float* __restrict__ R_ap) {
  __shared__ bf16_t ebuf[2][32 * 256];
  const int blk = blockIdx.x;              // 512 blocks
  const int b = blk >> 3, lc = blk & 7;
  const int tid = threadIdx.x, w = tid >> 6, lane = tid & 63;
  const int colw = w * 32, c = lane & 15, g = lane >> 4;
  const int l0 = lc * LGRP;

  bf16x8 wU[2][8], wA[2][8];
#pragma unroll
  for (int nt = 0; nt < 2; ++nt)
#pragma unroll
    for (int ks = 0; ks < 8; ++ks) {
      size_t off = (size_t)(colw + nt * 16 + c) * 512 + ks * 32 + g * 8;
      wU[nt][ks] = *(const bf16x8*)(wu1e + off);
      wA[nt][ks] = *(const bf16x8*)(wa1e + off);
    }

  float pue[2][2][4];
#pragma unroll
  for (int m = 0; m < 2; ++m)
#pragma unroll
    for (int nt = 0; nt < 2; ++nt)
#pragma unroll
      for (int rr = 0; rr < 4; ++rr)
        pue[m][nt][rr] = p_ue[(size_t)(b * KK + m * 16 + g * 4 + rr) * HH + colw + nt * 16 + c];

  f32x4 accU[2][2];
  const f32x4 z4 = {0.f, 0.f, 0.f, 0.f};
#pragma unroll
  for (int m = 0; m < 2; ++m)
#pragma unroll
    for (int nt = 0; nt < 2; ++nt) accU[m][nt] = z4;

  f32x4 rs[4];
  ld_tile(e + (size_t)((b * LL + l0) * KK) * HH, tid, rs);
  wr_tile(ebuf[0], tid, rs);

  for (int li = 0; li < LGRP; ++li) {
    __syncthreads();                       // ebuf[li&1] ready; ebuf[(li+1)&1] readers done
    const int l = l0 + li;
    if (li + 1 < LGRP) ld_tile(e + (size_t)((b * LL + l + 1) * KK) * HH, tid, rs);

    f32x4 aU[2][2], aA[2][2];
#pragma unroll
    for (int nt = 0; nt < 2; ++nt) {
      float pa = p_ap[(size_t)(b * LL + l) * HH + colw + nt * 16 + c];
      f32x4 t = {pa, pa, pa, pa};
      aA[0][nt] = t; aA[1][nt] = t;
#pragma unroll
      for (int rr = 0; rr < 4; ++rr) {
        aU[0][nt][rr] = pue[0][nt][rr];
        aU[1][nt][rr] = pue[1][nt][rr];
      }
    }
    const bf16_t* eb = ebuf[li & 1];
    const int swz = (c & 7) << 4;
#pragma unroll
    for (int ks = 0; ks < 8; ++ks) {
      const int kb = (ks * 32 + g * 8) * 2;
      bf16x8 a0 = *(const bf16x8*)((const char*)eb + c * 512 + (kb ^ swz));
      bf16x8 a1 = *(const bf16x8*)((const char*)eb + (16 + c) * 512 + (kb ^ swz));
#pragma unroll
      for (int nt = 0; nt < 2; ++nt) {
        aU[0][nt] = __builtin_amdgcn_mfma_f32_16x16x32_bf16(a0, wU[nt][ks], aU[0][nt], 0, 0, 0);
        aU[1][nt] = __builtin_amdgcn_mfma_f32_16x16x32_bf16(a1, wU[nt][ks], aU[1][nt], 0, 0, 0);
        aA[0][nt] = __builtin_amdgcn_mfma_f32_16x16x32_bf16(a0, wA[nt][ks], aA[0][nt], 0, 0, 0);
        aA[1][nt] = __builtin_amdgcn_mfma_f32_16x16x32_bf16(a1, wA[nt][ks], aA[1][nt], 0, 0, 0);
      }
    }

    // u2a: relu + k-reduce -> R_ap[b,l,:]  (no bias; /K folded in wu2s at m-GEMM)
#pragma unroll
    for (int nt = 0; nt < 2; ++nt) {
      float s = 0.f;
#pragma unroll
      for (int m = 0; m < 2; ++m)
#pragma unroll
        for (int rr = 0; rr < 4; ++rr) s += fmaxf(aU[m][nt][rr], 0.f);
      s += __shfl_xor(s, 16);
      s += __shfl_xor(s, 32);
      if (lane < 16)
        R_ap[(size_t)(b * LL + l) * HH + colw + nt * 16 + lane] = s;
    }
    // a2u: relu accumulate over l
#pragma unroll
    for (int m = 0; m < 2; ++m)
#pragma unroll
      for (int nt = 0; nt < 2; ++nt)
#pragma unroll
        for (int rr = 0; rr < 4; ++rr)
          accU[m][nt][rr] += fmaxf(aA[m][nt][rr], 0.f);

    // stage next tile last: global-load latency hidden under MFMA + reductions above
    if (li + 1 < LGRP) wr_tile(ebuf[(li + 1) & 1], tid, rs);
  }

#pragma unroll
  for (int m = 0; m < 2; ++m)
#pragma unroll
    for (int nt = 0; nt < 2; ++nt)
#pragma unroll
      for (int rr = 0; rr < 4; ++rr) {
        int krow = m * 16 + g * 4 + rr;
        part[(size_t)((lc * BB + b) * KK + krow) * HH + colw + nt * 16 + c] = accU[m][nt][rr];
      }
}

// ---------------- reduce partials -> R_ue (Σ_l relu; /L folded in wa2s) ----------------
__global__ __launch_bounds__(256) void reduce_kernel(
    const float* __restrict__ part, float* __restrict__ R_ue) {
  int i = blockIdx.x * 256 + threadIdx.x;
  float s = 0.f;
#pragma unroll
  for (int lc = 0; lc < 8; ++lc) s += part[(size_t)lc * 524288 + i];
  R_ue[i] = s;
}

// ---------------- merged GRUs (bf16 weights) ----------------
__global__ __launch_bounds__(256) void gru_kernel(
    const float* __restrict__ m_ue, const float* __restrict__ h_ue,
    const bf16_t* __restrict__ wih_ue, const bf16_t* __restrict__ whh_ue,
    const float* __restrict__ ue_bih, const float* __restrict__ ue_bhh,
    float* __restrict__ hue_new,
    const float* __restrict__ m_ap, const float* __restrict__ h_ap,
    const bf16_t* __restrict__ wih_ap, const bf16_t* __restrict__ whh_ap,
    const float* __restrict__ ap_bih, const float* __restrict__ ap_bhh,
    float* __restrict__ hap_new) {
  const int blk = blockIdx.x;
  const float *x, *h, *bih, *bhh; const bf16_t *wih, *whh; float* hout; int row0;
  if (blk < 64) { x = m_ue; h = h_ue; wih = wih_ue; whh = whh_ue;
                  bih = ue_bih; bhh = ue_bhh; hout = hue_new; row0 = blk * 32; }
  else          { x = m_ap; h = h_ap; wih = wih_ap; whh = whh_ap;
                  bih = ap_bih; bhh = ap_bhh; hout = hap_new; row0 = (blk - 64) * 32; }
  const int tid = threadIdx.x, w = tid >> 6, lane = tid & 63;
  const int colw = w * 64, c = lane & 15, g = lane >> 4;
  f32x4 aR[2][4], aZ[2][4], aN[2][4], aHN[2][4];
#pragma unroll
  for (int nt = 0; nt < 4; ++nt) {
    int col = colw + nt * 16 + c;
    float vR = bih[col] + bhh[col];
    float vZ = bih[256 + col] + bhh[256 + col];
    float vN = bih[512 + col];
    float vH = bhh[512 + col];
    f32x4 tR = {vR, vR, vR, vR}, tZ = {vZ, vZ, vZ, vZ};
    f32x4 tN = {vN, vN, vN, vN}, tH = {vH, vH, vH, vH};
    aR[0][nt] = tR; aR[1][nt] = tR;
    aZ[0][nt] = tZ; aZ[1][nt] = tZ;
    aN[0][nt] = tN; aN[1][nt] = tN;
    aHN[0][nt] = tH; aHN[1][nt] = tH;
  }
  const float* X = x + (size_t)row0 * HH;
  const float* Hp = h + (size_t)row0 * HH;
  mm_f32A<256>(X,  wih + (size_t)(0   + colw) * 256, aR, lane);
  mm_f32A<256>(Hp, whh + (size_t)(0   + colw) * 256, aR, lane);
  mm_f32A<256>(X,  wih + (size_t)(256 + colw) * 256, aZ, lane);
  mm_f32A<256>(Hp, whh + (size_t)(256 + colw) * 256, aZ, lane);
  mm_f32A<256>(X,  wih + (size_t)(512 + colw) * 256, aN, lane);
  mm_f32A<256>(Hp, whh + (size_t)(512 + colw) * 256, aHN, lane);
#pragma unroll
  for (int m = 0; m < 2; ++m)
#pragma unroll
    for (int nt = 0; nt < 4; ++nt)
#pragma unroll
      for (int rr = 0; rr < 4; ++rr) {
        int row = row0 + m * 16 + g * 4 + rr;
        int col = colw + nt * 16 + c;
        float rg = 1.f / (1.f + __expf(-aR[m][nt][rr]));
        float zg = 1.f / (1.f + __expf(-aZ[m][nt][rr]));
        float t = aN[m][nt][rr] + rg * aHN[m][nt][rr];
        t = fminf(fmaxf(t, -15.f), 15.f);
        float ex = __expf(-2.f * t);
        float ng = (1.f - ex) / (1.f + ex);
        float ho = h[(size_t)row * HH + col];
        hout[(size_t)row * HH + col] = (1.f - zg) * ng + zg * ho;
      }
}

// ---------------- phase C: edge update (weights in regs, 8 l's per block) ----------------
__global__ __launch_bounds__(512) void phaseC_kernel(
    const float* __restrict__ e, const float* __restrict__ q_ue,
    const float* __restrict__ q_ap,
    const bf16_t* __restrict__ wed1e, const bf16_t* __restrict__ wed2,
    const float* __restrict__ ed_b2, float* __restrict__ e_new) {
  __shared__ bf16_t ebuf[2][32 * 256];
  __shared__ bf16_t pbuf[32 * 256];
  const int blk = blockIdx.x;              // 512 blocks
  const int b = blk >> 3, lc = blk & 7;
  const int tid = threadIdx.x, w = tid >> 6, lane = tid & 63;
  const int colw = w * 32, c = lane & 15, g = lane >> 4;
  const int l0 = lc * LGRP;

  bf16x8 w1[2][8], w2[2][8];
#pragma unroll
  for (int nt = 0; nt < 2; ++nt)
#pragma unroll
    for (int ks = 0; ks < 8; ++ks) {
      w1[nt][ks] = *(const bf16x8*)(wed1e + (size_t)(colw + nt * 16 + c) * 768 + ks * 32 + g * 8);
      w2[nt][ks] = *(const bf16x8*)(wed2  + (size_t)(colw + nt * 16 + c) * 256 + ks * 32 + g * 8);
    }

  float qU[2][2][4];
#pragma unroll
  for (int m = 0; m < 2; ++m)
#pragma unroll
    for (int nt = 0; nt < 2; ++nt)
#pragma unroll
      for (int rr = 0; rr < 4; ++rr)
        qU[m][nt][rr] = q_ue[(size_t)(b * KK + m * 16 + g * 4 + rr) * HH + colw + nt * 16 + c];
  float b2v[2];
#pragma unroll
  for (int nt = 0; nt < 2; ++nt) b2v[nt] = ed_b2[colw + nt * 16 + c];

  f32x4 rs[4];
  ld_tile(e + (size_t)((b * LL + l0) * KK) * HH, tid, rs);
  wr_tile(ebuf[0], tid, rs);

  for (int li = 0; li < LGRP; ++li) {
    __syncthreads();                       // ebuf[li&1] ready; prev pbuf readers done
    const int l = l0 + li;

    f32x4 a1[2][2];
#pragma unroll
    for (int nt = 0; nt < 2; ++nt) {
      float qa = q_ap[(size_t)(b * LL + l) * HH + colw + nt * 16 + c];
#pragma unroll
      for (int rr = 0; rr < 4; ++rr) {
        a1[0][nt][rr] = qa + qU[0][nt][rr];
        a1[1][nt][rr] = qa + qU[1][nt][rr];
      }
    }
    const bf16_t* eb = ebuf[li & 1];
    const int swz = (c & 7) << 4;
#pragma unroll
    for (int ks = 0; ks < 8; ++ks) {
      const int kb = (ks * 32 + g * 8) * 2;
      bf16x8 a0 = *(const bf16x8*)((const char*)eb + c * 512 + (kb ^ swz));
      bf16x8 a1f = *(const bf16x8*)((const char*)eb + (16 + c) * 512 + (kb ^ swz));
#pragma unroll
      for (int nt = 0; nt < 2; ++nt) {
        a1[0][nt] = __builtin_amdgcn_mfma_f32_16x16x32_bf16(a0,  w1[nt][ks], a1[0][nt], 0, 0, 0);
        a1[1][nt] = __builtin_amdgcn_mfma_f32_16x16x32_bf16(a1f, w1[nt][ks], a1[1][nt], 0, 0, 0);
      }
    }
    if (li + 1 < LGRP) ld_tile(e + (size_t)((b * LL + l + 1) * KK) * HH, tid, rs);

    // relu -> pbuf (this wave's 32-col slice)
#pragma unroll
    for (int m = 0; m < 2; ++m)
#pragma unroll
      for (int nt = 0; nt < 2; ++nt)
#pragma unroll
        for (int rr = 0; rr < 4; ++rr) {
          int row = m * 16 + g * 4 + rr;
          int col = colw + nt * 16 + c;
          float v = fmaxf(a1[m][nt][rr], 0.f);
          int off = row * 512 + ((col * 2) ^ ((row & 7) << 4));
          *(bf16_t*)((char*)pbuf + off) = (__bf16)v;
        }
    __syncthreads();                       // pbuf visible

    f32x4 a2[2][2];
#pragma unroll
    for (int nt = 0; nt < 2; ++nt) {
      f32x4 t = {b2v[nt], b2v[nt], b2v[nt], b2v[nt]};
      a2[0][nt] = t; a2[1][nt] = t;
    }
#pragma unroll
    for (int ks = 0; ks < 8; ++ks) {
      const int kb = (ks * 32 + g * 8) * 2;
      bf16x8 a0 = *(const bf16x8*)((const char*)pbuf + c * 512 + (kb ^ swz));
      bf16x8 a1f = *(const bf16x8*)((const char*)pbuf + (16 + c) * 512 + (kb ^ swz));
#pragma unroll
      for (int nt = 0; nt < 2; ++nt) {
        a2[0][nt] = __builtin_amdgcn_mfma_f32_16x16x32_bf16(a0,  w2[nt][ks], a2[0][nt], 0, 0, 0);
        a2[1][nt] = __builtin_amdgcn_mfma_f32_16x16x32_bf16(a1f, w2[nt][ks], a2[1][nt], 0, 0, 0);
      }
    }
#pragma unroll
    for (int m = 0; m < 2; ++m)
#pragma unroll
      for (int nt = 0; nt < 2; ++nt)
#pragma unroll
        for (int rr = 0; rr < 4; ++rr) {
          int row = m * 16 + g * 4 + rr;
          int col = colw + nt * 16 + c;
          e_new[(size_t)((b * LL + l) * KK + row) * HH + col] = a2[m][nt][rr];
        }
    if (li + 1 < LGRP) wr_tile(ebuf[(li + 1) & 1], tid, rs);
  }
}

extern "C" void kernel_launch(void* const* d_in, const int* in_sizes, int n_in,
                              void* d_out, int out_size, void* d_ws, size_t ws_size,
                              hipStream_t stream) {
  const float* h_ue   = (const float*)d_in[0];
  const float* h_ap   = (const float*)d_in[1];
  const float* e      = (const float*)d_in[2];
  const float* a2u_w1 = (const float*)d_in[3];
  const float* a2u_b1 = (const float*)d_in[4];
  const float* a2u_w2 = (const float*)d_in[5];
  const float* a2u_b2 = (const float*)d_in[6];
  const float* u2a_w1 = (const float*)d_in[7];
  const float* u2a_b1 = (const float*)d_in[8];
  const float* u2a_w2 = (const float*)d_in[9];
  const float* u2a_b2 = (const float*)d_in[10];
  const float* ue_wih = (const float*)d_in[11];
  const float* ue_bih = (const float*)d_in[12];
  const float* ue_whh = (const float*)d_in[13];
  const float* ue_bhh = (const float*)d_in[14];
  const float* ap_wih = (const float*)d_in[15];
  const float* ap_bih = (const float*)d_in[16];
  const float* ap_whh = (const float*)d_in[17];
  const float* ap_bhh = (const float*)d_in[18];
  const float* ed_w1  = (const float*)d_in[19];
  const float* ed_b1  = (const float*)d_in[20];
  const float* ed_w2  = (const float*)d_in[21];
  const float* ed_b2  = (const float*)d_in[22];

  // workspace layout (bf16 weights, then f32 scratch) — R4-proven
  bf16_t* wb      = (bf16_t*)d_ws;
  bf16_t* wa1     = wb;                 // a2u_w1 (256x512)
  bf16_t* wa2s    = wa1 + 131072;       // a2u_w2 / 64
  bf16_t* wu1     = wa2s + 65536;       // u2a_w1 (256x512)
  bf16_t* wu2s    = wu1 + 131072;       // u2a_w2 / 32
  bf16_t* wih_ue  = wu2s + 65536;
  bf16_t* whh_ue  = wih_ue + 196608;
  bf16_t* wih_ap  = whh_ue + 196608;
  bf16_t* whh_ap  = wih_ap + 196608;
  bf16_t* wed1    = whh_ap + 196608;    // ed_w1 (256x768)
  bf16_t* wed2    = wed1 + 196608;      // ed_w2 (256x256)
  float* fbase = (float*)((char*)d_ws + 2883584);
  float* m_ue = fbase;                  // 524288
  float* m_ap = m_ue + 524288;          // 1048576
  float* p_ap = m_ap + 1048576;         // 1048576
  float* p_ue = p_ap + 1048576;         // 524288
  float* q_ue = p_ue + 524288;          // 524288  (aliased: R_ue before GRU)
  float* q_ap = q_ue + 524288;          // 1048576 (aliased: R_ap before GRU)
  float* part = q_ap + 1048576;         // 8 * 524288
  float* R_ue = q_ue;                   // dead before q_ue written
  float* R_ap = q_ap;                   // dead before q_ap written

  float* out      = (float*)d_out;
  float* hue_new  = out;                // 524288
  float* hap_new  = out + 524288;       // 1048576
  float* e_new    = out + 1572864;      // 33554432

  prep_kernel<<<5632, 256, 0, stream>>>(a2u_w1, a2u_w2, u2a_w1, u2a_w2,
                                        ue_wih, ue_whh, ap_wih, ap_whh,
                                        ed_w1, ed_w2, wb);
  // p_ap = h_ap*Wa1_h^T + b1 ; p_ue = h_ue*Wu1_h^T + b1
  proj2_kernel<512><<<192, 256, 0, stream>>>(h_ap, wa1, a2u_b1, p_ap, 128,
                                             h_ue, wu1, u2a_b1, p_ue);
  phaseA_kernel<<<512, 512, 0, stream>>>(e, p_ap, p_ue, wu1 + 256, wa1 + 256,
                                         part, R_ap);
  reduce_kernel<<<2048, 256, 0, stream>>>(part, R_ue);
  // m_ue = R_ue*(Wa2/L)^T + b2 ; m_ap = R_ap*(Wu2/K)^T + b2
  proj2_kernel<256><<<192, 256, 0, stream>>>(R_ue, wa2s, a2u_b2, m_ue, 64,
                                             R_ap, wu2s, u2a_b2, m_ap);
  gru_kernel<<<192, 256, 0, stream>>>(m_ue, h_ue, wih_ue, whh_ue, ue_bih, ue_bhh, hue_new,
                                      m_ap, h_ap, wih_ap, whh_ap, ap_bih, ap_bhh, hap_new);
  // q_ue = hue_new*Wed1[:, :H]^T + ed_b1 ; q_ap = hap_new*Wed1[:, H:2H]^T
  proj2_kernel<768><<<192, 256, 0, stream>>>(hue_new, wed1, ed_b1, q_ue, 64,
                                             hap_new, wed1 + 256, nullptr, q_ap);
  phaseC_kernel<<<512, 512, 0, stream>>>(e, q_ue, q_ap, wed1 + 512, wed2, ed_b2, e_new);
}

// Round 11
// 214.724 us; speedup vs baseline: 1.3380x; 1.0049x over previous
//
#include <hip/hip_runtime.h>

#define HH 256   // H
#define BB 64    // B
#define KK 32    // K
#define LL 64    // L
#define LGRP 8   // l's per edge-kernel block

typedef __bf16 bf16_t;
typedef __attribute__((ext_vector_type(8))) __bf16 bf16x8;
typedef __attribute__((ext_vector_type(4))) float f32x4;

// ---- load 8 contiguous f32, convert to bf16x8 ----
__device__ __forceinline__ bf16x8 ld_a8(const float* __restrict__ p) {
  const f32x4* q = (const f32x4*)p;
  f32x4 a = q[0], b = q[1];
  bf16x8 r;
  r[0] = (__bf16)a[0]; r[1] = (__bf16)a[1]; r[2] = (__bf16)a[2]; r[3] = (__bf16)a[3];
  r[4] = (__bf16)b[0]; r[5] = (__bf16)b[1]; r[6] = (__bf16)b[2]; r[7] = (__bf16)b[3];
  return r;
}

// ---- e-tile staging (512 threads): 16 f32/thread -> regs -> swizzled bf16 LDS ----
__device__ __forceinline__ void ld_tile(const float* __restrict__ E, int tid, f32x4 r[4]) {
  const f32x4* q = (const f32x4*)(E + tid * 16);
  r[0] = q[0]; r[1] = q[1]; r[2] = q[2]; r[3] = q[3];
}
__device__ __forceinline__ void wr_tile(bf16_t* buf, int tid, const f32x4 r[4]) {
  int row = tid >> 4;
  int colb = (tid & 15) * 32;
  bf16x8 v0, v1;
  v0[0] = (__bf16)r[0][0]; v0[1] = (__bf16)r[0][1]; v0[2] = (__bf16)r[0][2]; v0[3] = (__bf16)r[0][3];
  v0[4] = (__bf16)r[1][0]; v0[5] = (__bf16)r[1][1]; v0[6] = (__bf16)r[1][2]; v0[7] = (__bf16)r[1][3];
  v1[0] = (__bf16)r[2][0]; v1[1] = (__bf16)r[2][1]; v1[2] = (__bf16)r[2][2]; v1[3] = (__bf16)r[2][3];
  v1[4] = (__bf16)r[3][0]; v1[5] = (__bf16)r[3][1]; v1[6] = (__bf16)r[3][2]; v1[7] = (__bf16)r[3][3];
  int swz = (row & 7) << 4;
  *(bf16x8*)((char*)buf + row * 512 + (colb ^ swz)) = v0;
  *(bf16x8*)((char*)buf + row * 512 + ((colb + 16) ^ swz)) = v1;
}

// acc[2][4] += A(32x256 f32 global)*B(bf16 row-major)^T  (4-wave kernels, 64-col wave)
template<int LDB>
__device__ __forceinline__ void mm_f32A(const float* __restrict__ A,
                                        const bf16_t* __restrict__ B,
                                        f32x4 acc[2][4], int lane) {
  const int c = lane & 15, g = lane >> 4;
#pragma unroll
  for (int ks = 0; ks < 8; ++ks) {
    const int ko = ks * 32 + g * 8;
    bf16x8 a0 = ld_a8(A + (size_t)c * HH + ko);
    bf16x8 a1 = ld_a8(A + (size_t)(16 + c) * HH + ko);
#pragma unroll
    for (int nt = 0; nt < 4; ++nt) {
      bf16x8 bb = *(const bf16x8*)(B + (size_t)(nt * 16 + c) * LDB + ko);
      acc[0][nt] = __builtin_amdgcn_mfma_f32_16x16x32_bf16(a0, bb, acc[0][nt], 0, 0, 0);
      acc[1][nt] = __builtin_amdgcn_mfma_f32_16x16x32_bf16(a1, bb, acc[1][nt], 0, 0, 0);
    }
  }
}

// ---------------- prep: all weights f32->bf16 (layer-2 msg weights pre-scaled) ----------------
__global__ __launch_bounds__(256) void prep_kernel(
    const float* w0, const float* w1, const float* w2, const float* w3,
    const float* w4, const float* w5, const float* w6, const float* w7,
    const float* w8, const float* w9, bf16_t* wb) {
  int i = blockIdx.x * 256 + threadIdx.x;
  const float* s; int o; float sc = 1.f;
  if      (i < 131072)  { s = w0; o = i; }
  else if (i < 196608)  { s = w1; o = i - 131072; sc = 1.f / 64.f; }   // a2u_w2 / L
  else if (i < 327680)  { s = w2; o = i - 196608; }
  else if (i < 393216)  { s = w3; o = i - 327680; sc = 1.f / 32.f; }   // u2a_w2 / K
  else if (i < 589824)  { s = w4; o = i - 393216; }
  else if (i < 786432)  { s = w5; o = i - 589824; }
  else if (i < 983040)  { s = w6; o = i - 786432; }
  else if (i < 1179648) { s = w7; o = i - 983040; }
  else if (i < 1376256) { s = w8; o = i - 1179648; }
  else                  { s = w9; o = i - 1376256; }
  wb[i] = (__bf16)(s[o] * sc);
}

// ---------------- fused pair of projections: out = X*W^T + bias ----------------
template<int LDW>
__global__ __launch_bounds__(256) void proj2_kernel(
    const float* __restrict__ X0, const bf16_t* __restrict__ W0,
    const float* __restrict__ b0, float* __restrict__ out0, int n0,
    const float* __restrict__ X1, const bf16_t* __restrict__ W1,
    const float* __restrict__ b1, float* __restrict__ out1) {
  const int blk = blockIdx.x;
  const float* X; const bf16_t* W; const float* bias; float* out; int row0;
  if (blk < n0) { X = X0; W = W0; bias = b0; out = out0; row0 = blk * 32; }
  else          { X = X1; W = W1; bias = b1; out = out1; row0 = (blk - n0) * 32; }
  const int tid = threadIdx.x, w = tid >> 6, lane = tid & 63;
  const int colw = w * 64, c = lane & 15, g = lane >> 4;
  f32x4 acc[2][4];
#pragma unroll
  for (int nt = 0; nt < 4; ++nt) {
    float bv = bias ? bias[colw + nt * 16 + c] : 0.f;
    f32x4 t = {bv, bv, bv, bv};
    acc[0][nt] = t; acc[1][nt] = t;
  }
  mm_f32A<LDW>(X + (size_t)row0 * HH, W + (size_t)colw * LDW, acc, lane);
#pragma unroll
  for (int m = 0; m < 2; ++m)
#pragma unroll
    for (int nt = 0; nt < 4; ++nt)
#pragma unroll
      for (int rr = 0; rr < 4; ++rr) {
        int row = row0 + m * 16 + g * 4 + rr;
        out[(size_t)row * HH + colw + nt * 16 + c] = acc[m][nt][rr];
      }
}

// ---------------- phase A: layer-1 of both message MLPs, relu, reductions ----------------
// 512 threads = 8 waves; wave owns 32 output cols; bf16 weights register-resident.
// ONE barrier per l-iteration (R10-proven).
__global__ __launch_bounds__(512) void phaseA_kernel(
    const float* __restrict__ e, const float* __restrict__ p_ap,
    const float* __restrict__ p_ue,
    const bf16_t* __restrict__ wu1e, const bf16_t* __restrict__ wa1e,
    float* __restrict__ part, float* __restrict__ R_ap) {
  __shared__ bf16_t ebuf[2][32 * 256];
  const int blk = blockIdx.x;              // 512 blocks
  const int b = blk >> 3, lc = blk & 7;
  const int tid = threadIdx.x, w = tid >> 6, lane = tid & 63;
  const int colw = w * 32, c = lane & 15, g = lane >> 4;
  const int l0 = lc * LGRP;

  bf16x8 wU[2][8], wA[2][8];
#pragma unroll
  for (int nt = 0; nt < 2; ++nt)
#pragma unroll
    for (int ks = 0; ks < 8; ++ks) {
      size_t off = (size_t)(colw + nt * 16 + c) * 512 + ks * 32 + g * 8;
      wU[nt][ks] = *(const bf16x8*)(wu1e + off);
      wA[nt][ks] = *(const bf16x8*)(wa1e + off);
    }

  float pue[2][2][4];
#pragma unroll
  for (int m = 0; m < 2; ++m)
#pragma unroll
    for (int nt = 0; nt < 2; ++nt)
#pragma unroll
      for (int rr = 0; rr < 4; ++rr)
        pue[m][nt][rr] = p_ue[(size_t)(b * KK + m * 16 + g * 4 + rr) * HH + colw + nt * 16 + c];

  f32x4 accU[2][2];
  const f32x4 z4 = {0.f, 0.f, 0.f, 0.f};
#pragma unroll
  for (int m = 0; m < 2; ++m)
#pragma unroll
    for (int nt = 0; nt < 2; ++nt) accU[m][nt] = z4;

  f32x4 rs[4];
  ld_tile(e + (size_t)((b * LL + l0) * KK) * HH, tid, rs);
  wr_tile(ebuf[0], tid, rs);

  for (int li = 0; li < LGRP; ++li) {
    __syncthreads();                       // ebuf[li&1] ready; ebuf[(li+1)&1] readers done
    const int l = l0 + li;
    if (li + 1 < LGRP) ld_tile(e + (size_t)((b * LL + l + 1) * KK) * HH, tid, rs);

    f32x4 aU[2][2], aA[2][2];
#pragma unroll
    for (int nt = 0; nt < 2; ++nt) {
      float pa = p_ap[(size_t)(b * LL + l) * HH + colw + nt * 16 + c];
      f32x4 t = {pa, pa, pa, pa};
      aA[0][nt] = t; aA[1][nt] = t;
#pragma unroll
      for (int rr = 0; rr < 4; ++rr) {
        aU[0][nt][rr] = pue[0][nt][rr];
        aU[1][nt][rr] = pue[1][nt][rr];
      }
    }
    const bf16_t* eb = ebuf[li & 1];
    const int swz = (c & 7) << 4;
#pragma unroll
    for (int ks = 0; ks < 8; ++ks) {
      const int kb = (ks * 32 + g * 8) * 2;
      bf16x8 a0 = *(const bf16x8*)((const char*)eb + c * 512 + (kb ^ swz));
      bf16x8 a1 = *(const bf16x8*)((const char*)eb + (16 + c) * 512 + (kb ^ swz));
#pragma unroll
      for (int nt = 0; nt < 2; ++nt) {
        aU[0][nt] = __builtin_amdgcn_mfma_f32_16x16x32_bf16(a0, wU[nt][ks], aU[0][nt], 0, 0, 0);
        aU[1][nt] = __builtin_amdgcn_mfma_f32_16x16x32_bf16(a1, wU[nt][ks], aU[1][nt], 0, 0, 0);
        aA[0][nt] = __builtin_amdgcn_mfma_f32_16x16x32_bf16(a0, wA[nt][ks], aA[0][nt], 0, 0, 0);
        aA[1][nt] = __builtin_amdgcn_mfma_f32_16x16x32_bf16(a1, wA[nt][ks], aA[1][nt], 0, 0, 0);
      }
    }

    // u2a: relu + k-reduce -> R_ap[b,l,:]  (no bias; /K folded in wu2s at m-GEMM)
#pragma unroll
    for (int nt = 0; nt < 2; ++nt) {
      float s = 0.f;
#pragma unroll
      for (int m = 0; m < 2; ++m)
#pragma unroll
        for (int rr = 0; rr < 4; ++rr) s += fmaxf(aU[m][nt][rr], 0.f);
      s += __shfl_xor(s, 16);
      s += __shfl_xor(s, 32);
      if (lane < 16)
        R_ap[(size_t)(b * LL + l) * HH + colw + nt * 16 + lane] = s;
    }
    // a2u: relu accumulate over l
#pragma unroll
    for (int m = 0; m < 2; ++m)
#pragma unroll
      for (int nt = 0; nt < 2; ++nt)
#pragma unroll
        for (int rr = 0; rr < 4; ++rr)
          accU[m][nt][rr] += fmaxf(aA[m][nt][rr], 0.f);

    if (li + 1 < LGRP) wr_tile(ebuf[(li + 1) & 1], tid, rs);
  }

#pragma unroll
  for (int m = 0; m < 2; ++m)
#pragma unroll
    for (int nt = 0; nt < 2; ++nt)
#pragma unroll
      for (int rr = 0; rr < 4; ++rr) {
        int krow = m * 16 + g * 4 + rr;
        part[(size_t)((lc * BB + b) * KK + krow) * HH + colw + nt * 16 + c] = accU[m][nt][rr];
      }
}

// ---------------- reduce partials -> R_ue (Σ_l relu; /L folded in wa2s) ----------------
__global__ __launch_bounds__(256) void reduce_kernel(
    const float* __restrict__ part, float* __restrict__ R_ue) {
  int i = blockIdx.x * 256 + threadIdx.x;
  float s = 0.f;
#pragma unroll
  for (int lc = 0; lc < 8; ++lc) s += part[(size_t)lc * 524288 + i];
  R_ue[i] = s;
}

// ---------------- merged GRUs (bf16 weights) ----------------
__global__ __launch_bounds__(256) void gru_kernel(
    const float* __restrict__ m_ue, const float* __restrict__ h_ue,
    const bf16_t* __restrict__ wih_ue, const bf16_t* __restrict__ whh_ue,
    const float* __restrict__ ue_bih, const float* __restrict__ ue_bhh,
    float* __restrict__ hue_new,
    const float* __restrict__ m_ap, const float* __restrict__ h_ap,
    const bf16_t* __restrict__ wih_ap, const bf16_t* __restrict__ whh_ap,
    const float* __restrict__ ap_bih, const float* __restrict__ ap_bhh,
    float* __restrict__ hap_new) {
  const int blk = blockIdx.x;
  const float *x, *h, *bih, *bhh; const bf16_t *wih, *whh; float* hout; int row0;
  if (blk < 64) { x = m_ue; h = h_ue; wih = wih_ue; whh = whh_ue;
                  bih = ue_bih; bhh = ue_bhh; hout = hue_new; row0 = blk * 32; }
  else          { x = m_ap; h = h_ap; wih = wih_ap; whh = whh_ap;
                  bih = ap_bih; bhh = ap_bhh; hout = hap_new; row0 = (blk - 64) * 32; }
  const int tid = threadIdx.x, w = tid >> 6, lane = tid & 63;
  const int colw = w * 64, c = lane & 15, g = lane >> 4;
  f32x4 aR[2][4], aZ[2][4], aN[2][4], aHN[2][4];
#pragma unroll
  for (int nt = 0; nt < 4; ++nt) {
    int col = colw + nt * 16 + c;
    float vR = bih[col] + bhh[col];
    float vZ = bih[256 + col] + bhh[256 + col];
    float vN = bih[512 + col];
    float vH = bhh[512 + col];
    f32x4 tR = {vR, vR, vR, vR}, tZ = {vZ, vZ, vZ, vZ};
    f32x4 tN = {vN, vN, vN, vN}, tH = {vH, vH, vH, vH};
    aR[0][nt] = tR; aR[1][nt] = tR;
    aZ[0][nt] = tZ; aZ[1][nt] = tZ;
    aN[0][nt] = tN; aN[1][nt] = tN;
    aHN[0][nt] = tH; aHN[1][nt] = tH;
  }
  const float* X = x + (size_t)row0 * HH;
  const float* Hp = h + (size_t)row0 * HH;
  mm_f32A<256>(X,  wih + (size_t)(0   + colw) * 256, aR, lane);
  mm_f32A<256>(Hp, whh + (size_t)(0   + colw) * 256, aR, lane);
  mm_f32A<256>(X,  wih + (size_t)(256 + colw) * 256, aZ, lane);
  mm_f32A<256>(Hp, whh + (size_t)(256 + colw) * 256, aZ, lane);
  mm_f32A<256>(X,  wih + (size_t)(512 + colw) * 256, aN, lane);
  mm_f32A<256>(Hp, whh + (size_t)(512 + colw) * 256, aHN, lane);
#pragma unroll
  for (int m = 0; m < 2; ++m)
#pragma unroll
    for (int nt = 0; nt < 4; ++nt)
#pragma unroll
      for (int rr = 0; rr < 4; ++rr) {
        int row = row0 + m * 16 + g * 4 + rr;
        int col = colw + nt * 16 + c;
        float rg = 1.f / (1.f + __expf(-aR[m][nt][rr]));
        float zg = 1.f / (1.f + __expf(-aZ[m][nt][rr]));
        float t = aN[m][nt][rr] + rg * aHN[m][nt][rr];
        t = fminf(fmaxf(t, -15.f), 15.f);
        float ex = __expf(-2.f * t);
        float ng = (1.f - ex) / (1.f + ex);
        float ho = h[(size_t)row * HH + col];
        hout[(size_t)row * HH + col] = (1.f - zg) * ng + zg * ho;
      }
}

// ---------------- phase C: edge update, software-pipelined two-GEMM chain ----------------
// pbuf double-buffered; iter li computes layer-1 for tile li (-> pbuf[li&1]) and
// layer-2 for tile li-1 (from pbuf[(li-1)&1], visible since the top barrier).
// ONE barrier per iteration (was 2): pbuf[li&1]'s previous readers ran in iter li-1
// and passed this barrier; ebuf[(li+1)&1]'s readers likewise.
__global__ __launch_bounds__(512) void phaseC_kernel(
    const float* __restrict__ e, const float* __restrict__ q_ue,
    const float* __restrict__ q_ap,
    const bf16_t* __restrict__ wed1e, const bf16_t* __restrict__ wed2,
    const float* __restrict__ ed_b2, float* __restrict__ e_new) {
  __shared__ bf16_t ebuf[2][32 * 256];
  __shared__ bf16_t pbuf[2][32 * 256];
  const int blk = blockIdx.x;              // 512 blocks
  const int b = blk >> 3, lc = blk & 7;
  const int tid = threadIdx.x, w = tid >> 6, lane = tid & 63;
  const int colw = w * 32, c = lane & 15, g = lane >> 4;
  const int l0 = lc * LGRP;

  bf16x8 w1[2][8], w2[2][8];
#pragma unroll
  for (int nt = 0; nt < 2; ++nt)
#pragma unroll
    for (int ks = 0; ks < 8; ++ks) {
      w1[nt][ks] = *(const bf16x8*)(wed1e + (size_t)(colw + nt * 16 + c) * 768 + ks * 32 + g * 8);
      w2[nt][ks] = *(const bf16x8*)(wed2  + (size_t)(colw + nt * 16 + c) * 256 + ks * 32 + g * 8);
    }

  float qU[2][2][4];
#pragma unroll
  for (int m = 0; m < 2; ++m)
#pragma unroll
    for (int nt = 0; nt < 2; ++nt)
#pragma unroll
      for (int rr = 0; rr < 4; ++rr)
        qU[m][nt][rr] = q_ue[(size_t)(b * KK + m * 16 + g * 4 + rr) * HH + colw + nt * 16 + c];
  float b2v[2];
#pragma unroll
  for (int nt = 0; nt < 2; ++nt) b2v[nt] = ed_b2[colw + nt * 16 + c];

  const int swz = (c & 7) << 4;

  f32x4 rs[4];
  ld_tile(e + (size_t)((b * LL + l0) * KK) * HH, tid, rs);
  wr_tile(ebuf[0], tid, rs);

  for (int li = 0; li < LGRP; ++li) {
    __syncthreads();   // ebuf[li&1] + pbuf[(li-1)&1] ready; pbuf[li&1]/ebuf[(li+1)&1] readers done
    const int l = l0 + li;
    if (li + 1 < LGRP) ld_tile(e + (size_t)((b * LL + l + 1) * KK) * HH, tid, rs);

    // ---- layer-2 for tile li-1 (pbuf[(li-1)&1]) -> e_new[l-1] ----
    if (li > 0) {
      const bf16_t* pb = pbuf[(li - 1) & 1];
      f32x4 a2[2][2];
#pragma unroll
      for (int nt = 0; nt < 2; ++nt) {
        f32x4 t = {b2v[nt], b2v[nt], b2v[nt], b2v[nt]};
        a2[0][nt] = t; a2[1][nt] = t;
      }
#pragma unroll
      for (int ks = 0; ks < 8; ++ks) {
        const int kb = (ks * 32 + g * 8) * 2;
        bf16x8 a0 = *(const bf16x8*)((const char*)pb + c * 512 + (kb ^ swz));
        bf16x8 a1f = *(const bf16x8*)((const char*)pb + (16 + c) * 512 + (kb ^ swz));
#pragma unroll
        for (int nt = 0; nt < 2; ++nt) {
          a2[0][nt] = __builtin_amdgcn_mfma_f32_16x16x32_bf16(a0,  w2[nt][ks], a2[0][nt], 0, 0, 0);
          a2[1][nt] = __builtin_amdgcn_mfma_f32_16x16x32_bf16(a1f, w2[nt][ks], a2[1][nt], 0, 0, 0);
        }
      }
#pragma unroll
      for (int m = 0; m < 2; ++m)
#pragma unroll
        for (int nt = 0; nt < 2; ++nt)
#pragma unroll
          for (int rr = 0; rr < 4; ++rr) {
            int row = m * 16 + g * 4 + rr;
            int col = colw + nt * 16 + c;
            e_new[(size_t)((b * LL + l - 1) * KK + row) * HH + col] = a2[m][nt][rr];
          }
    }

    // ---- layer-1 for tile li (ebuf[li&1]) -> relu -> pbuf[li&1] ----
    f32x4 a1[2][2];
#pragma unroll
    for (int nt = 0; nt < 2; ++nt) {
      float qa = q_ap[(size_t)(b * LL + l) * HH + colw + nt * 16 + c];
#pragma unroll
      for (int rr = 0; rr < 4; ++rr) {
        a1[0][nt][rr] = qa + qU[0][nt][rr];
        a1[1][nt][rr] = qa + qU[1][nt][rr];
      }
    }
    const bf16_t* eb = ebuf[li & 1];
#pragma unroll
    for (int ks = 0; ks < 8; ++ks) {
      const int kb = (ks * 32 + g * 8) * 2;
      bf16x8 a0 = *(const bf16x8*)((const char*)eb + c * 512 + (kb ^ swz));
      bf16x8 a1f = *(const bf16x8*)((const char*)eb + (16 + c) * 512 + (kb ^ swz));
#pragma unroll
      for (int nt = 0; nt < 2; ++nt) {
        a1[0][nt] = __builtin_amdgcn_mfma_f32_16x16x32_bf16(a0,  w1[nt][ks], a1[0][nt], 0, 0, 0);
        a1[1][nt] = __builtin_amdgcn_mfma_f32_16x16x32_bf16(a1f, w1[nt][ks], a1[1][nt], 0, 0, 0);
      }
    }
    bf16_t* pw = pbuf[li & 1];
#pragma unroll
    for (int m = 0; m < 2; ++m)
#pragma unroll
      for (int nt = 0; nt < 2; ++nt)
#pragma unroll
        for (int rr = 0; rr < 4; ++rr) {
          int row = m * 16 + g * 4 + rr;
          int col = colw + nt * 16 + c;
          float v = fmaxf(a1[m][nt][rr], 0.f);
          int off = row * 512 + ((col * 2) ^ ((row & 7) << 4));
          *(bf16_t*)((char*)pw + off) = (__bf16)v;
        }

    if (li + 1 < LGRP) wr_tile(ebuf[(li + 1) & 1], tid, rs);
  }

  // ---- epilogue: layer-2 for the last tile ----
  __syncthreads();
  {
    const bf16_t* pb = pbuf[(LGRP - 1) & 1];
    f32x4 a2[2][2];
#pragma unroll
    for (int nt = 0; nt < 2; ++nt) {
      f32x4 t = {b2v[nt], b2v[nt], b2v[nt], b2v[nt]};
      a2[0][nt] = t; a2[1][nt] = t;
    }
#pragma unroll
    for (int ks = 0; ks < 8; ++ks) {
      const int kb = (ks * 32 + g * 8) * 2;
      bf16x8 a0 = *(const bf16x8*)((const char*)pb + c * 512 + (kb ^ swz));
      bf16x8 a1f = *(const bf16x8*)((const char*)pb + (16 + c) * 512 + (kb ^ swz));
#pragma unroll
      for (int nt = 0; nt < 2; ++nt) {
        a2[0][nt] = __builtin_amdgcn_mfma_f32_16x16x32_bf16(a0,  w2[nt][ks], a2[0][nt], 0, 0, 0);
        a2[1][nt] = __builtin_amdgcn_mfma_f32_16x16x32_bf16(a1f, w2[nt][ks], a2[1][nt], 0, 0, 0);
      }
    }
#pragma unroll
    for (int m = 0; m < 2; ++m)
#pragma unroll
      for (int nt = 0; nt < 2; ++nt)
#pragma unroll
        for (int rr = 0; rr < 4; ++rr) {
          int row = m * 16 + g * 4 + rr;
          int col = colw + nt * 16 + c;
          e_new[(size_t)((b * LL + l0 + LGRP - 1) * KK + row) * HH + col] = a2[m][nt][rr];
        }
  }
}

extern "C" void kernel_launch(void* const* d_in, const int* in_sizes, int n_in,
                              void* d_out, int out_size, void* d_ws, size_t ws_size,
                              hipStream_t stream) {
  const float* h_ue   = (const float*)d_in[0];
  const float* h_ap   = (const float*)d_in[1];
  const float* e      = (const float*)d_in[2];
  const float* a2u_w1 = (const float*)d_in[3];
  const float* a2u_b1 = (const float*)d_in[4];
  const float* a2u_w2 = (const float*)d_in[5];
  const float* a2u_b2 = (const float*)d_in[6];
  const float* u2a_w1 = (const float*)d_in[7];
  const float* u2a_b1 = (const float*)d_in[8];
  const float* u2a_w2 = (const float*)d_in[9];
  const float* u2a_b2 = (const float*)d_in[10];
  const float* ue_wih = (const float*)d_in[11];
  const float* ue_bih = (const float*)d_in[12];
  const float* ue_whh = (const float*)d_in[13];
  const float* ue_bhh = (const float*)d_in[14];
  const float* ap_wih = (const float*)d_in[15];
  const float* ap_bih = (const float*)d_in[16];
  const float* ap_whh = (const float*)d_in[17];
  const float* ap_bhh = (const float*)d_in[18];
  const float* ed_w1  = (const float*)d_in[19];
  const float* ed_b1  = (const float*)d_in[20];
  const float* ed_w2  = (const float*)d_in[21];
  const float* ed_b2  = (const float*)d_in[22];

  // workspace layout (bf16 weights, then f32 scratch) — R4-proven
  bf16_t* wb      = (bf16_t*)d_ws;
  bf16_t* wa1     = wb;                 // a2u_w1 (256x512)
  bf16_t* wa2s    = wa1 + 131072;       // a2u_w2 / 64
  bf16_t* wu1     = wa2s + 65536;       // u2a_w1 (256x512)
  bf16_t* wu2s    = wu1 + 131072;       // u2a_w2 / 32
  bf16_t* wih_ue  = wu2s + 65536;
  bf16_t* whh_ue  = wih_ue + 196608;
  bf16_t* wih_ap  = whh_ue + 196608;
  bf16_t* whh_ap  = wih_ap + 196608;
  bf16_t* wed1    = whh_ap + 196608;    // ed_w1 (256x768)
  bf16_t* wed2    = wed1 + 196608;      // ed_w2 (256x256)
  float* fbase = (float*)((char*)d_ws + 2883584);
  float* m_ue = fbase;                  // 524288
  float* m_ap = m_ue + 524288;          // 1048576
  float* p_ap = m_ap + 1048576;         // 1048576
  float* p_ue = p_ap + 1048576;         // 524288
  float* q_ue = p_ue + 524288;          // 524288  (aliased: R_ue before GRU)
  float* q_ap = q_ue + 524288;          // 1048576 (aliased: R_ap before GRU)
  float* part = q_ap + 1048576;         // 8 * 524288
  float* R_ue = q_ue;                   // dead before q_ue written
  float* R_ap = q_ap;                   // dead before q_ap written

  float* out      = (float*)d_out;
  float* hue_new  = out;                // 524288
  float* hap_new  = out + 524288;       // 1048576
  float* e_new    = out + 1572864;      // 33554432

  prep_kernel<<<5632, 256, 0, stream>>>(a2u_w1, a2u_w2, u2a_w1, u2a_w2,
                                        ue_wih, ue_whh, ap_wih, ap_whh,
                                        ed_w1, ed_w2, wb);
  // p_ap = h_ap*Wa1_h^T + b1 ; p_ue = h_ue*Wu1_h^T + b1
  proj2_kernel<512><<<192, 256, 0, stream>>>(h_ap, wa1, a2u_b1, p_ap, 128,
                                             h_ue, wu1, u2a_b1, p_ue);
  phaseA_kernel<<<512, 512, 0, stream>>>(e, p_ap, p_ue, wu1 + 256, wa1 + 256,
                                         part, R_ap);
  reduce_kernel<<<2048, 256, 0, stream>>>(part, R_ue);
  // m_ue = R_ue*(Wa2/L)^T + b2 ; m_ap = R_ap*(Wu2/K)^T + b2
  proj2_kernel<256><<<192, 256, 0, stream>>>(R_ue, wa2s, a2u_b2, m_ue, 64,
                                             R_ap, wu2s, u2a_b2, m_ap);
  gru_kernel<<<192, 256, 0, stream>>>(m_ue, h_ue, wih_ue, whh_ue, ue_bih, ue_bhh, hue_new,
                                      m_ap, h_ap, wih_ap, whh_ap, ap_bih, ap_bhh, hap_new);
  // q_ue = hue_new*Wed1[:, :H]^T + ed_b1 ; q_ap = hap_new*Wed1[:, H:2H]^T
  proj2_kernel<768><<<192, 256, 0, stream>>>(hue_new, wed1, ed_b1, q_ue, 64,
                                             hap_new, wed1 + 256, nullptr, q_ap);
  phaseC_kernel<<<512, 512, 0, stream>>>(e, q_ue, q_ap, wed1 + 512, wed2, ed_b2, e_new);
}